// Round 5
// baseline (1942.106 us; speedup 1.0000x reference)
//
#include <hip/hip_runtime.h>
#include <hip/hip_fp16.h>
#include <math.h>

#define NN 50000
#define EE 800000
#define HH 128
#define KIT 10
#define NHF (NN * HH)     // 6,400,000 elements per snapshot
#define CC 64             // edge chunks
#define CH 12500          // edges per chunk (divisible by 4; byte offset 16B-aligned)
#define RRH 4             // node ranges per mode
#define NRH 12500         // nodes per range (50KB LDS)
#define GFUSE 1024        // fused prop grid: 4 blocks/CU x 256 CU (exact-fit residency)

typedef _Float16 half8 __attribute__((ext_vector_type(8)));
typedef _Float16 half4v __attribute__((ext_vector_type(4)));
typedef float floatx4 __attribute__((ext_vector_type(4)));

static_assert(NN % 16 == 0, "row tiles must be exact");

__device__ __forceinline__ float gelu_exact(float x) {
  return 0.5f * x * (1.f + erff(x * 0.70710678118654752f));
}

// typed 4-float load/store helpers (fp32 or fp16 storage)
__device__ __forceinline__ float4 ld4(const float* p) { return *(const float4*)p; }
__device__ __forceinline__ float4 ld4(const __half* p) {
  const __half2* q = (const __half2*)p;
  float2 lo = __half22float2(q[0]);
  float2 hi = __half22float2(q[1]);
  return make_float4(lo.x, lo.y, hi.x, hi.y);
}
__device__ __forceinline__ void st1(float* p, float v) { *p = v; }
__device__ __forceinline__ void st1(__half* p, float v) { *p = __float2half_rn(v); }

// ---------------- graph preprocessing (NO global atomics) ----------------
__global__ __launch_bounds__(256) void hist2_kernel(const int* __restrict__ ei,
                                                    const float* __restrict__ ew,
                                                    int* __restrict__ pdeg,
                                                    float* __restrict__ pwsum,
                                                    int* __restrict__ rank) {
  __shared__ int hist[NRH];
  const int c = blockIdx.x;
  const int z = blockIdx.y;
  const bool isdeg = (z < RRH);
  const int lo = (isdeg ? z : z - RRH) * NRH;
  for (int i = threadIdx.x; i < NRH; i += 256) hist[i] = 0;   // 0 bits == 0.f
  __syncthreads();
  const int e0 = c * CH;
  if (isdeg) {
    const int4* d4 = (const int4*)(ei + (size_t)EE + e0);
    for (int i = threadIdx.x; i < CH / 4; i += 256) {
      int4 d = d4[i];
      int e = e0 + i * 4;
      unsigned u0 = (unsigned)(d.x - lo), u1 = (unsigned)(d.y - lo);
      unsigned u2 = (unsigned)(d.z - lo), u3 = (unsigned)(d.w - lo);
      if (u0 < NRH) rank[e]     = atomicAdd(&hist[u0], 1);
      if (u1 < NRH) rank[e + 1] = atomicAdd(&hist[u1], 1);
      if (u2 < NRH) rank[e + 2] = atomicAdd(&hist[u2], 1);
      if (u3 < NRH) rank[e + 3] = atomicAdd(&hist[u3], 1);
    }
    __syncthreads();
    for (int i = threadIdx.x; i < NRH; i += 256)
      pdeg[(size_t)c * NN + lo + i] = hist[i];
  } else {
    float* whist = (float*)hist;
    const int4* s4 = (const int4*)(ei + e0);
    const float4* w4 = (const float4*)(ew + e0);
    for (int i = threadIdx.x; i < CH / 4; i += 256) {
      int4 s = s4[i];
      float4 w = w4[i];
      unsigned u0 = (unsigned)(s.x - lo), u1 = (unsigned)(s.y - lo);
      unsigned u2 = (unsigned)(s.z - lo), u3 = (unsigned)(s.w - lo);
      if (u0 < NRH) atomicAdd(&whist[u0], w.x);
      if (u1 < NRH) atomicAdd(&whist[u1], w.y);
      if (u2 < NRH) atomicAdd(&whist[u2], w.z);
      if (u3 < NRH) atomicAdd(&whist[u3], w.w);
    }
    __syncthreads();
    for (int i = threadIdx.x; i < NRH; i += 256)
      pwsum[(size_t)c * NN + lo + i] = whist[i];
  }
}

// per-node: deg = sum over chunks (pdeg -> in-place exclusive chunk prefix),
// wsum = sum over chunks; block-reduce PADDED deg -> bsum (rows padded to mult of 8).
__global__ __launch_bounds__(256) void reduce_kernel(int* __restrict__ pdeg,
                                                     const float* __restrict__ pwsum,
                                                     int* __restrict__ deg,
                                                     float* __restrict__ wsum,
                                                     int* __restrict__ bsum) {
  int node = blockIdx.x * 256 + threadIdx.x;
  int acc = 0; float wacc = 0.f;
  if (node < NN) {
    for (int c = 0; c < CC; ++c) {
      size_t idx = (size_t)c * NN + node;
      int t = pdeg[idx];
      pdeg[idx] = acc;        // exclusive prefix over chunks
      acc += t;
      wacc += pwsum[idx];
    }
    deg[node] = acc;          // real degree
    wsum[node] = wacc;
  }
  __shared__ int red[256];
  red[threadIdx.x] = (node < NN) ? ((acc + 7) & ~7) : 0;   // padded degree
  __syncthreads();
  for (int off = 128; off > 0; off >>= 1) {
    if (threadIdx.x < off) red[threadIdx.x] += red[threadIdx.x + off];
    __syncthreads();
  }
  if (threadIdx.x == 0) bsum[blockIdx.x] = red[0];
}

__global__ __launch_bounds__(256) void scan2_kernel(const int* __restrict__ bsum,
                                                    int* __restrict__ boff,
                                                    int* __restrict__ row_start, int nb, int n) {
  __shared__ int buf[256];
  int tid = threadIdx.x;
  int v = (tid < nb) ? bsum[tid] : 0;
  buf[tid] = v;
  __syncthreads();
  for (int off = 1; off < 256; off <<= 1) {
    int t = (tid >= off) ? buf[tid - off] : 0;
    __syncthreads();
    buf[tid] += t;
    __syncthreads();
  }
  if (tid < nb) boff[tid] = buf[tid] - v;  // exclusive prefix
  if (tid == 255) row_start[n] = buf[255];
}

// scan over PADDED degrees -> row_start
__global__ __launch_bounds__(256) void scan3_kernel(const int* __restrict__ deg,
                                                    const int* __restrict__ boff,
                                                    int* __restrict__ row_start, int n) {
  __shared__ int buf[256];
  int tid = threadIdx.x;
  int i = blockIdx.x * 256 + tid;
  int v = (i < n) ? ((deg[i] + 7) & ~7) : 0;
  buf[tid] = v;
  __syncthreads();
  for (int off = 1; off < 256; off <<= 1) {
    int t = (tid >= off) ? buf[tid - off] : 0;
    __syncthreads();
    buf[tid] += t;
    __syncthreads();
  }
  if (i < n) row_start[i] = boff[blockIdx.x] + buf[tid] - v;
}

__global__ __launch_bounds__(256) void csr_fill_kernel(const int* __restrict__ ei,
                                                       const float* __restrict__ ew,
                                                       const float* __restrict__ wsum,
                                                       const int* __restrict__ row_start,
                                                       const int* __restrict__ pdeg_excl,
                                                       const int* __restrict__ rank,
                                                       int2* __restrict__ csr, int e_cnt) {
  int e = blockIdx.x * 256 + threadIdx.x;
  if (e >= e_cnt) return;
  int c = e / CH;
  int src = ei[e], dst = ei[EE + e];
  float ws = wsum[src];
  ws = ws < 1.f ? 1.f : ws;
  float v = 0.9f * ew[e] / ws;            // (1-ALPHA) * enorm folded together
  int pos = row_start[dst] + pdeg_excl[(size_t)c * NN + dst] + rank[e];
  csr[pos] = make_int2(src, __float_as_int(v));
}

// fill pad slots with (src=0, w=+0.f) AND zero the global-barrier state.
__global__ __launch_bounds__(256) void pad_fill_kernel(const int* __restrict__ deg,
                                                       const int* __restrict__ row_start,
                                                       long* __restrict__ csr,
                                                       int* __restrict__ bar) {
  if (blockIdx.x == 0 && threadIdx.x < 128) bar[threadIdx.x] = 0;
  int node = blockIdx.x * 256 + threadIdx.x;
  if (node >= NN) return;
  int s = row_start[node] + deg[node];
  int e = row_start[node + 1];
  for (int i = s; i < e; ++i) csr[i] = 0;
}

// ---------------- propagation body: one wave per 2 consecutive nodes, fp16 h -------------
// CSR rows padded to multiples of 8 -> tail-free. Two consecutive nodes have CONTIGUOUS
// CSR segments; one pipelined 8-edge batch stream covers both; wave-uniform flag selects
// the accumulator. (R2-proven version, bit-identical accumulation order.)
__device__ __forceinline__ void prop_pair(int nA, int lane,
                                          const __half2* __restrict__ hc,
                                          const __half2* __restrict__ bp,
                                          const int* __restrict__ row_start,
                                          const long* __restrict__ csr,
                                          __half2* __restrict__ np) {
  int nB = nA + 1;
  float2 vbA = __half22float2(bp[(size_t)nA * 64 + lane]);
  float2 vbB = __half22float2(bp[(size_t)nB * 64 + lane]);
  float aAx = 0.1f * vbA.x, aAy = 0.1f * vbA.y, bAx = 0.f, bAy = 0.f;
  float aBx = 0.1f * vbB.x, aBy = 0.1f * vbB.y, bBx = 0.f, bBy = 0.f;
  int s  = __builtin_amdgcn_readfirstlane(row_start[nA]);
  int eA = __builtin_amdgcn_readfirstlane(row_start[nA + 1]);
  int eB = __builtin_amdgcn_readfirstlane(row_start[nB + 1]);
  int nb = (eB - s) >> 3;          // all batches full (padded)
  int i = s;
  if (nb > 0) {
    long cur[8];
    bool curB = (i >= eA);
#pragma unroll
    for (int j = 0; j < 8; ++j) cur[j] = csr[i + j];
    i += 8;
    for (int bidx = 1; bidx < nb; ++bidx) {
      long nxt[8];
      bool nxtB = (i >= eA);
#pragma unroll
      for (int j = 0; j < 8; ++j) nxt[j] = csr[i + j];
      i += 8;
      float2 g[8];
#pragma unroll
      for (int j = 0; j < 8; ++j) g[j] = __half22float2(hc[(size_t)(int)cur[j] * 64 + lane]);
      if (curB) {
#pragma unroll
        for (int j = 0; j < 8; ++j) {
          float v = __int_as_float((int)(cur[j] >> 32));
          if (j & 1) { bBx = fmaf(v, g[j].x, bBx); bBy = fmaf(v, g[j].y, bBy); }
          else       { aBx = fmaf(v, g[j].x, aBx); aBy = fmaf(v, g[j].y, aBy); }
        }
      } else {
#pragma unroll
        for (int j = 0; j < 8; ++j) {
          float v = __int_as_float((int)(cur[j] >> 32));
          if (j & 1) { bAx = fmaf(v, g[j].x, bAx); bAy = fmaf(v, g[j].y, bAy); }
          else       { aAx = fmaf(v, g[j].x, aAx); aAy = fmaf(v, g[j].y, aAy); }
        }
      }
#pragma unroll
      for (int j = 0; j < 8; ++j) cur[j] = nxt[j];
      curB = nxtB;
    }
    float2 g[8];
#pragma unroll
    for (int j = 0; j < 8; ++j) g[j] = __half22float2(hc[(size_t)(int)cur[j] * 64 + lane]);
    if (curB) {
#pragma unroll
      for (int j = 0; j < 8; ++j) {
        float v = __int_as_float((int)(cur[j] >> 32));
        if (j & 1) { bBx = fmaf(v, g[j].x, bBx); bBy = fmaf(v, g[j].y, bBy); }
        else       { aBx = fmaf(v, g[j].x, aBx); aBy = fmaf(v, g[j].y, aBy); }
      }
    } else {
#pragma unroll
      for (int j = 0; j < 8; ++j) {
        float v = __int_as_float((int)(cur[j] >> 32));
        if (j & 1) { bAx = fmaf(v, g[j].x, bAx); bAy = fmaf(v, g[j].y, bAy); }
        else       { aAx = fmaf(v, g[j].x, aAx); aAy = fmaf(v, g[j].y, aAy); }
      }
    }
  }
  np[(size_t)nA * 64 + lane] = __float22half2_rn(make_float2(aAx + bAx, aAy + bAy));
  np[(size_t)nB * 64 + lane] = __float22half2_rn(make_float2(aBx + bBx, aBy + bBy));
}

// per-iteration prop (non-stored fallback path)
__global__ __launch_bounds__(256, 6) void prop_kernel(const __half* __restrict__ h_cur,
                                                      const __half* __restrict__ base,
                                                      const int* __restrict__ row_start,
                                                      const long* __restrict__ csr,
                                                      __half* __restrict__ h_next) {
  int pair = __builtin_amdgcn_readfirstlane((int)blockIdx.x * 4 + (int)(threadIdx.x >> 6));
  if (pair * 2 >= NN) return;
  prop_pair(pair * 2, threadIdx.x & 63, (const __half2*)h_cur, (const __half2*)base,
            row_start, csr, (__half2*)h_next);
}

// fused propagation: all KIT iterations in ONE plain dispatch (graph-capture safe).
// Exact-fit grid 1024 blocks = 4/CU (launch_bounds(256,4), VGPR<=128, LDS=0 -> all
// co-resident). Two-level epoch barrier in global memory with AGENT-scope atomics:
// bar[0..63] sub-counters (16 blocks each), bar[64] master, bar[65] monotonic flag.
__global__ __launch_bounds__(256, 4) void prop_fused_kernel(__half* XS,
                                                            const int* __restrict__ row_start,
                                                            const long* __restrict__ csr,
                                                            int* bar, int niter) {
  const int TOTW = GFUSE * 4;
  const int wid = (int)blockIdx.x * 4 + (int)(threadIdx.x >> 6);
  const int lane = threadIdx.x & 63;
  const __half2* bp = (const __half2*)XS;
  for (int k = 0; k < niter; ++k) {
    const __half2* hcp = (const __half2*)(XS + (size_t)k * NHF);
    __half2* npp = (__half2*)(XS + (size_t)(k + 1) * NHF);
    for (int pr = wid; pr < NN / 2; pr += TOTW)
      prop_pair(pr * 2, lane, hcp, bp, row_start, csr, npp);
    if (k == niter - 1) break;     // last hand-off handled by stream ordering
    __syncthreads();               // block's writes complete
    if (threadIdx.x == 0) {
      __threadfence();             // flush this XCD's L2 (release block writes)
      int s = (int)blockIdx.x & 63;
      int v = __hip_atomic_fetch_add(&bar[s], 1, __ATOMIC_ACQ_REL,
                                     __HIP_MEMORY_SCOPE_AGENT);
      if (v == (GFUSE / 64) - 1) {             // last of this sub-group
        __hip_atomic_store(&bar[s], 0, __ATOMIC_RELAXED, __HIP_MEMORY_SCOPE_AGENT);
        int m = __hip_atomic_fetch_add(&bar[64], 1, __ATOMIC_ACQ_REL,
                                       __HIP_MEMORY_SCOPE_AGENT);
        if (m == 63) {                          // last sub-group -> release epoch
          __hip_atomic_store(&bar[64], 0, __ATOMIC_RELAXED, __HIP_MEMORY_SCOPE_AGENT);
          __hip_atomic_store(&bar[65], k + 1, __ATOMIC_RELEASE,
                             __HIP_MEMORY_SCOPE_AGENT);
        }
      }
      while (__hip_atomic_load(&bar[65], __ATOMIC_ACQUIRE,
                               __HIP_MEMORY_SCOPE_AGENT) < k + 1)
        __builtin_amdgcn_s_sleep(2);
      __threadfence();             // invalidate stale lines before next-iter reads
    }
    __syncthreads();
  }
}

// ---------------- MFMA dense v2: out[n][j] = act(sum_k X[n][k] * W[j][k] + ...) ----------
// One 16-row tile per wave. X rows wave-private -> A-fragments direct from global; only W
// staged in LDS (fp16, XOR-swizzled). FG variant: A-fragment computed on the fly as
// sum_k attw[row][k] * XS_k[row][c..c+8] (fp32 accum, fp16 convert — bit-identical to the
// old fused_gather->head1 pipeline).
template <int K, int KA, int JP, int JR, int ACT, bool RESID, typename IT, typename OT,
          bool FG = false>
__global__ __launch_bounds__(256) void mfma_dense2(
    const IT* __restrict__ Xa, const IT* __restrict__ Xb,
    const float* __restrict__ W, const float* __restrict__ lb,
    const float* __restrict__ bg, const float* __restrict__ bb,
    const float* __restrict__ bm, const float* __restrict__ bv,
    const OT* __restrict__ resid, OT* __restrict__ out,
    const float* __restrict__ attwp = nullptr) {
  static_assert(K % 32 == 0 && KA % 32 == 0 && JP % 16 == 0, "");
  constexpr int JT = JP / 16;      // 16-col MFMA tiles
  constexpr int NS = K / 32;       // K-slices of 32
  constexpr bool ISF = __is_same(IT, float);
  __shared__ _Float16 wL[JP][K];   // swizzled: 16B chunk c stored at chunk (c ^ (j&7))

  const int tid = threadIdx.x;
  const int wv = tid >> 6, lane = tid & 63;
  const int q = lane >> 4, m = lane & 15;
  const int t = blockIdx.x * 4 + wv;           // tile id (16 rows)
  const bool active = (t < NN / 16);
  const int row = t * 16 + m;

  // ---- issue per-lane A-fragment loads (direct global, 16B each) ----
  half8  a[ISF ? 1 : NS];
  float4 af0[ISF ? NS : 1], af1[ISF ? NS : 1];
  float awr[FG ? 12 : 1];
  if (active) {
    if constexpr (FG) {
      *(float4*)&awr[0] = *(const float4*)&attwp[row * 16 + 0];
      *(float4*)&awr[4] = *(const float4*)&attwp[row * 16 + 4];
      *(float4*)&awr[8] = *(const float4*)&attwp[row * 16 + 8];
    } else {
#pragma unroll
      for (int s = 0; s < NS; ++s) {
        int c = s * 32 + q * 8;
        if constexpr (ISF) {
          const float* p = (const float*)Xa + (size_t)row * K + c;
          af0[s] = *(const float4*)p;
          af1[s] = *(const float4*)(p + 4);
        } else {
          const __half* p = (c < KA) ? (const __half*)Xa + (size_t)row * KA + c
                                     : (const __half*)Xb + (size_t)row * (K - KA) + (c - KA);
          a[s] = *(const half8*)p;
        }
      }
    }
  }

  // ---- stage W: fp32 -> fp16, swizzled LDS; zero-fill rows j >= JR ----
  constexpr int C4 = K / 4;
  for (int idx = tid; idx < JP * C4; idx += 256) {
    int j = idx / C4;
    int c4 = (idx % C4) * 4;
    float4 v = make_float4(0.f, 0.f, 0.f, 0.f);
    if (j < JR) v = *(const float4*)&W[(size_t)j * K + c4];
    int cs = ((((c4 >> 3) ^ (j & 7)) << 3) | (c4 & 7));
    *(half4v*)&wL[j][cs] = (half4v){(_Float16)v.x, (_Float16)v.y,
                                    (_Float16)v.z, (_Float16)v.w};
  }
  __syncthreads();

  if (!active) return;

  floatx4 acc[JT];
#pragma unroll
  for (int jt = 0; jt < JT; ++jt) acc[jt] = (floatx4)(0.f);

#pragma unroll
  for (int s = 0; s < NS; ++s) {
    half8 av;
    if constexpr (FG) {
      float f[8] = {0.f, 0.f, 0.f, 0.f, 0.f, 0.f, 0.f, 0.f};
      const __half* bptr = (const __half*)Xa + (size_t)row * K + (s * 32 + q * 8);
#pragma unroll
      for (int k = 0; k <= KIT; ++k) {
        half8 v = *(const half8*)(bptr + (size_t)k * NHF);
#pragma unroll
        for (int e = 0; e < 8; ++e) f[e] = fmaf(awr[k], (float)v[e], f[e]);
      }
      av = (half8){(_Float16)f[0], (_Float16)f[1], (_Float16)f[2], (_Float16)f[3],
                   (_Float16)f[4], (_Float16)f[5], (_Float16)f[6], (_Float16)f[7]};
    } else if constexpr (ISF) {
      float4 f0 = af0[s], f1 = af1[s];
      av = (half8){(_Float16)f0.x, (_Float16)f0.y, (_Float16)f0.z, (_Float16)f0.w,
                   (_Float16)f1.x, (_Float16)f1.y, (_Float16)f1.z, (_Float16)f1.w};
    } else {
      av = a[s];
    }
    int kq = s * 4 + q;                        // 16B chunk index within row
#pragma unroll
    for (int jt = 0; jt < JT; ++jt) {
      int j = jt * 16 + m;
      half8 b = *(const half8*)&wL[j][(kq ^ (j & 7)) << 3];
      acc[jt] = __builtin_amdgcn_mfma_f32_16x16x32_f16(av, b, acc[jt], 0, 0, 0);
    }
  }

  // epilogue: lane holds col j = jt*16 + m, rows q*4 + reg
#pragma unroll
  for (int jt = 0; jt < JT; ++jt) {
    int j = jt * 16 + m;
    if (j >= JR) continue;
    float sc = 0.f, sh;
    if (ACT == 1) {
      sc = bg[j] * rsqrtf(bv[j] + 1e-5f);
      sh = (lb[j] - bm[j]) * sc + bb[j];
    } else {
      sh = lb[j];
    }
#pragma unroll
    for (int reg = 0; reg < 4; ++reg) {
      int r = t * 16 + q * 4 + reg;
      float aa = acc[jt][reg];
      float y;
      if (ACT == 0)      y = aa + sh;
      else if (ACT == 1) y = fmaxf(fmaf(aa, sc, sh), 0.f);
      else               y = gelu_exact(aa + sh);
      if (RESID) y += (float)resid[(size_t)r * JR + j];
      st1(&out[(size_t)r * JR + j], y);
    }
  }
}

// ---------------- att2 (64 -> 11) + softmax, one thread per node ----------------
__global__ __launch_bounds__(64) void att2_softmax_kernel(const __half* __restrict__ g,
                                                          const float* __restrict__ W2,
                                                          const float* __restrict__ b2,
                                                          float* __restrict__ attw, int n_rows) {
  __shared__ float gl[64][65];
  int r0 = blockIdx.x * 64;
  for (int idx = threadIdx.x; idx < 64 * 16; idx += 64) {
    int r = idx >> 4, c4 = (idx & 15) * 4;
    float4 v = make_float4(0.f, 0.f, 0.f, 0.f);
    if (r0 + r < n_rows) v = ld4(&g[(size_t)(r0 + r) * 64 + c4]);
    gl[r][c4] = v.x; gl[r][c4 + 1] = v.y; gl[r][c4 + 2] = v.z; gl[r][c4 + 3] = v.w;
  }
  __syncthreads();
  int r = threadIdx.x;
  int n = r0 + r;
  if (n >= n_rows) return;
  float a[KIT + 1];
#pragma unroll
  for (int j = 0; j < KIT + 1; ++j) {
    float acc = b2[j];
#pragma unroll
    for (int k = 0; k < 64; ++k) acc = fmaf(gl[r][k], W2[j * 64 + k], acc);
    a[j] = acc;
  }
  float mx = a[0];
#pragma unroll
  for (int j = 1; j < KIT + 1; ++j) mx = fmaxf(mx, a[j]);
  float s = 0.f;
#pragma unroll
  for (int j = 0; j < KIT + 1; ++j) { a[j] = expf(a[j] - mx); s += a[j]; }
  float inv = 1.f / s;
#pragma unroll
  for (int j = 0; j < KIT + 1; ++j) attw[n * 16 + j] = a[j] * inv;
}

// recompute-path variant: fused (+)= attw[:,k] * h (h fp16, fused fp32 for accumulation)
__global__ __launch_bounds__(256) void fused_accum_kernel(const __half* __restrict__ h,
                                                          const float* __restrict__ attw,
                                                          float* __restrict__ fused, int k) {
  int node = __builtin_amdgcn_readfirstlane((int)blockIdx.x * 4 + (int)(threadIdx.x >> 6));
  if (node >= NN) return;
  int lane = threadIdx.x & 63;
  float wk = attw[node * 16 + k];
  float2 v = __half22float2(((const __half2*)h)[(size_t)node * 64 + lane]);
  float2 o;
  if (k == 0) {
    o = make_float2(wk * v.x, wk * v.y);
  } else {
    float2 f = ((const float2*)fused)[(size_t)node * 64 + lane];
    o = make_float2(fmaf(wk, v.x, f.x), fmaf(wk, v.y, f.y));
  }
  ((float2*)fused)[(size_t)node * 64 + lane] = o;
}

extern "C" void kernel_launch(void* const* d_in, const int* in_sizes, int n_in,
                              void* d_out, int out_size, void* d_ws, size_t ws_size,
                              hipStream_t stream) {
  (void)in_sizes; (void)n_in; (void)out_size;
  const float* x      = (const float*)d_in[0];
  const int*   ei     = (const int*)d_in[1];
  const float* ew     = (const float*)d_in[2];
  const float* lin1_w = (const float*)d_in[3];
  const float* lin1_b = (const float*)d_in[4];
  const float* bn1_g  = (const float*)d_in[5];
  const float* bn1_b  = (const float*)d_in[6];
  const float* bn1_m  = (const float*)d_in[7];
  const float* bn1_v  = (const float*)d_in[8];
  const float* lin2_w = (const float*)d_in[9];
  const float* lin2_b = (const float*)d_in[10];
  const float* bn2_g  = (const float*)d_in[11];
  const float* bn2_b  = (const float*)d_in[12];
  const float* bn2_m  = (const float*)d_in[13];
  const float* bn2_v  = (const float*)d_in[14];
  const float* att1_w = (const float*)d_in[15];
  const float* att1_b = (const float*)d_in[16];
  const float* att2_w = (const float*)d_in[17];
  const float* att2_b = (const float*)d_in[18];
  const float* head1_w= (const float*)d_in[19];
  const float* head1_b= (const float*)d_in[20];
  const float* bn3_g  = (const float*)d_in[21];
  const float* bn3_b  = (const float*)d_in[22];
  const float* bn3_m  = (const float*)d_in[23];
  const float* bn3_v  = (const float*)d_in[24];
  const float* head2_w= (const float*)d_in[25];
  const float* head2_b= (const float*)d_in[26];
  float* out = (float*)d_out;

  char* p = (char*)d_ws;
  auto alloc = [&](size_t bytes) -> void* {
    void* r = (void*)p;
    p += (bytes + 255) & ~(size_t)255;
    return r;
  };
  // persistent buffers (live across whole launch)
  int*   row_start= (int*)alloc((size_t)(NN + 1) * 4);
  int*   bsum     = (int*)alloc((size_t)256 * 4);
  int*   boff     = (int*)alloc((size_t)256 * 4);
  int*   bar      = (int*)alloc((size_t)256 * 4);   // global-barrier state (zeroed in pad_fill)
  int*   deg      = (int*)alloc((size_t)NN * 4);
  float* wsum     = (float*)alloc((size_t)NN * 4);
  long*  csr      = (long*)alloc(((size_t)EE + 8 * NN) * 8);  // padded rows (<=7/node)
  __half* gbuf    = (__half*)alloc((size_t)NN * 64 * 2);
  float* attw     = (float*)alloc((size_t)NN * 16 * 4);
  __half* h1      = (__half*)alloc((size_t)NHF * 2);
  __half* zbuf    = (__half*)alloc((size_t)NN * 64 * 2);
  size_t common = (size_t)(p - (char*)d_ws);
  size_t stored_need = common + (size_t)(KIT + 1) * NHF * 2 + 4096;
  bool stored = ws_size >= stored_need;

  // preprocessing temporaries overlay XS[8..10] (dead until prop k=7) in stored path.
  __half* XS = nullptr;
  int* pdeg; float* pwsum; int* rank;
  if (stored) {
    XS = (__half*)alloc((size_t)(KIT + 1) * NHF * 2);
    char* ovl = (char*)(XS + (size_t)8 * NHF);
    pdeg  = (int*)ovl;
    pwsum = (float*)(ovl + (size_t)CC * NN * 4);
    rank  = (int*)(ovl + 2 * (size_t)CC * NN * 4);
  } else {
    pdeg  = (int*)alloc((size_t)CC * NN * 4);
    pwsum = (float*)alloc((size_t)CC * NN * 4);
    rank  = (int*)alloc((size_t)EE * 4);
  }

  const int GE  = (EE + 255) / 256;          // edge-parallel grid
  const int GN  = (NN + 255) / 256;          // node-parallel grid (196)
  const int GT  = (NN / 16 + 3) / 4;         // dense v2 grid: 3125 wave-tiles -> 782 blocks
  const int GP  = (NN + 3) / 4;              // wave-per-node grids (12500)
  const int GP2 = (NN / 2 + 3) / 4;          // wave-per-2-nodes prop grid (6250)
  const int GA  = (NN + 63) / 64;            // att2 grid

  // graph preprocessing (atomic-free)
  hist2_kernel<<<dim3(CC, 2 * RRH), 256, 0, stream>>>(ei, ew, pdeg, pwsum, rank);
  reduce_kernel<<<GN, 256, 0, stream>>>(pdeg, pwsum, deg, wsum, bsum);
  scan2_kernel<<<1, 256, 0, stream>>>(bsum, boff, row_start, GN, NN);
  scan3_kernel<<<GN, 256, 0, stream>>>(deg, boff, row_start, NN);
  csr_fill_kernel<<<GE, 256, 0, stream>>>(ei, ew, wsum, row_start, pdeg, rank,
                                          (int2*)csr, EE);
  pad_fill_kernel<<<GN, 256, 0, stream>>>(deg, row_start, csr, bar);

  if (stored) {
    mfma_dense2<128, 128, 128, 128, 1, false, float, __half><<<GT, 256, 0, stream>>>(
        x, (const float*)nullptr, lin1_w, lin1_b, bn1_g, bn1_b, bn1_m, bn1_v, nullptr, h1);
    mfma_dense2<128, 128, 128, 128, 1, true, __half, __half><<<GT, 256, 0, stream>>>(
        h1, (const __half*)nullptr, lin2_w, lin2_b, bn2_g, bn2_b, bn2_m, bn2_v, h1, XS);
    prop_fused_kernel<<<GFUSE, 256, 0, stream>>>(XS, row_start, csr, bar, KIT);
    mfma_dense2<256, 128, 64, 64, 2, false, __half, __half><<<GT, 256, 0, stream>>>(
        XS, XS + (size_t)KIT * NHF, att1_w, att1_b, nullptr, nullptr, nullptr, nullptr,
        nullptr, gbuf);
    att2_softmax_kernel<<<GA, 64, 0, stream>>>(gbuf, att2_w, att2_b, attw, NN);
    // head1 with inline attention-fusion of the 11 snapshots (FG=true)
    mfma_dense2<128, 128, 64, 64, 1, false, __half, __half, true><<<GT, 256, 0, stream>>>(
        XS, (const __half*)nullptr, head1_w, head1_b, bn3_g, bn3_b, bn3_m, bn3_v,
        nullptr, zbuf, attw);
  } else {
    float*  fusedF = (float*)alloc((size_t)NHF * 4);
    __half* base   = (__half*)alloc((size_t)NHF * 2);
    __half* hA     = (__half*)alloc((size_t)NHF * 2);
    __half* hB     = (__half*)alloc((size_t)NHF * 2);
    mfma_dense2<128, 128, 128, 128, 1, false, float, __half><<<GT, 256, 0, stream>>>(
        x, (const float*)nullptr, lin1_w, lin1_b, bn1_g, bn1_b, bn1_m, bn1_v, nullptr, h1);
    mfma_dense2<128, 128, 128, 128, 1, true, __half, __half><<<GT, 256, 0, stream>>>(
        h1, (const __half*)nullptr, lin2_w, lin2_b, bn2_g, bn2_b, bn2_m, bn2_v, h1, base);
    // pass 1: get xs10
    const __half* cur = base;
    for (int k = 1; k <= KIT; ++k) {
      __half* nxt = (k & 1) ? hA : hB;
      prop_kernel<<<GP2, 256, 0, stream>>>(cur, base, row_start, csr, nxt);
      cur = nxt;
    }
    mfma_dense2<256, 128, 64, 64, 2, false, __half, __half><<<GT, 256, 0, stream>>>(
        base, cur, att1_w, att1_b, nullptr, nullptr, nullptr, nullptr, nullptr, gbuf);
    att2_softmax_kernel<<<GA, 64, 0, stream>>>(gbuf, att2_w, att2_b, attw, NN);
    // pass 2: re-propagate, accumulate fused on the fly (fp32 accumulator)
    fused_accum_kernel<<<GP, 256, 0, stream>>>(base, attw, fusedF, 0);
    cur = base;
    for (int k = 1; k <= KIT; ++k) {
      __half* nxt = (k & 1) ? hA : hB;
      prop_kernel<<<GP2, 256, 0, stream>>>(cur, base, row_start, csr, nxt);
      fused_accum_kernel<<<GP, 256, 0, stream>>>(nxt, attw, fusedF, k);
      cur = nxt;
    }
    mfma_dense2<128, 128, 64, 64, 1, false, float, __half><<<GT, 256, 0, stream>>>(
        fusedF, (const float*)nullptr, head1_w, head1_b, bn3_g, bn3_b, bn3_m, bn3_v,
        nullptr, zbuf);
  }

  // head2 (z fp16 -> out fp32)
  mfma_dense2<64, 64, 48, 40, 0, false, __half, float><<<GT, 256, 0, stream>>>(
      zbuf, (const __half*)nullptr, head2_w, head2_b, nullptr, nullptr, nullptr, nullptr,
      nullptr, out);
}

// Round 6
// 565.831 us; speedup vs baseline: 3.4323x; 3.4323x over previous
//
#include <hip/hip_runtime.h>
#include <hip/hip_fp16.h>
#include <math.h>

#define NN 50000
#define EE 800000
#define HH 128
#define KIT 10
#define NHF (NN * HH)     // 6,400,000 elements per snapshot
#define CC 64             // edge chunks
#define CH 12500          // edges per chunk (divisible by 4; byte offset 16B-aligned)
#define RRH 4             // node ranges per mode
#define NRH 12500         // nodes per range (50KB LDS)

typedef _Float16 half8 __attribute__((ext_vector_type(8)));
typedef _Float16 half4v __attribute__((ext_vector_type(4)));
typedef float floatx4 __attribute__((ext_vector_type(4)));

static_assert(NN % 16 == 0, "row tiles must be exact");

__device__ __forceinline__ float gelu_exact(float x) {
  return 0.5f * x * (1.f + erff(x * 0.70710678118654752f));
}

// typed 4-float load/store helpers (fp32 or fp16 storage)
__device__ __forceinline__ float4 ld4(const float* p) { return *(const float4*)p; }
__device__ __forceinline__ float4 ld4(const __half* p) {
  const __half2* q = (const __half2*)p;
  float2 lo = __half22float2(q[0]);
  float2 hi = __half22float2(q[1]);
  return make_float4(lo.x, lo.y, hi.x, hi.y);
}
__device__ __forceinline__ void st1(float* p, float v) { *p = v; }
__device__ __forceinline__ void st1(__half* p, float v) { *p = __float2half_rn(v); }

// ---------------- graph preprocessing (NO global atomics) ----------------
__global__ __launch_bounds__(256) void hist2_kernel(const int* __restrict__ ei,
                                                    const float* __restrict__ ew,
                                                    int* __restrict__ pdeg,
                                                    float* __restrict__ pwsum,
                                                    int* __restrict__ rank) {
  __shared__ int hist[NRH];
  const int c = blockIdx.x;
  const int z = blockIdx.y;
  const bool isdeg = (z < RRH);
  const int lo = (isdeg ? z : z - RRH) * NRH;
  for (int i = threadIdx.x; i < NRH; i += 256) hist[i] = 0;   // 0 bits == 0.f
  __syncthreads();
  const int e0 = c * CH;
  if (isdeg) {
    const int4* d4 = (const int4*)(ei + (size_t)EE + e0);
    for (int i = threadIdx.x; i < CH / 4; i += 256) {
      int4 d = d4[i];
      int e = e0 + i * 4;
      unsigned u0 = (unsigned)(d.x - lo), u1 = (unsigned)(d.y - lo);
      unsigned u2 = (unsigned)(d.z - lo), u3 = (unsigned)(d.w - lo);
      if (u0 < NRH) rank[e]     = atomicAdd(&hist[u0], 1);
      if (u1 < NRH) rank[e + 1] = atomicAdd(&hist[u1], 1);
      if (u2 < NRH) rank[e + 2] = atomicAdd(&hist[u2], 1);
      if (u3 < NRH) rank[e + 3] = atomicAdd(&hist[u3], 1);
    }
    __syncthreads();
    for (int i = threadIdx.x; i < NRH; i += 256)
      pdeg[(size_t)c * NN + lo + i] = hist[i];
  } else {
    float* whist = (float*)hist;
    const int4* s4 = (const int4*)(ei + e0);
    const float4* w4 = (const float4*)(ew + e0);
    for (int i = threadIdx.x; i < CH / 4; i += 256) {
      int4 s = s4[i];
      float4 w = w4[i];
      unsigned u0 = (unsigned)(s.x - lo), u1 = (unsigned)(s.y - lo);
      unsigned u2 = (unsigned)(s.z - lo), u3 = (unsigned)(s.w - lo);
      if (u0 < NRH) atomicAdd(&whist[u0], w.x);
      if (u1 < NRH) atomicAdd(&whist[u1], w.y);
      if (u2 < NRH) atomicAdd(&whist[u2], w.z);
      if (u3 < NRH) atomicAdd(&whist[u3], w.w);
    }
    __syncthreads();
    for (int i = threadIdx.x; i < NRH; i += 256)
      pwsum[(size_t)c * NN + lo + i] = whist[i];
  }
}

// per-node: deg = sum over chunks (pdeg -> in-place exclusive chunk prefix),
// wsum = sum over chunks; block-reduce PADDED deg -> bsum (rows padded to mult of 8).
__global__ __launch_bounds__(256) void reduce_kernel(int* __restrict__ pdeg,
                                                     const float* __restrict__ pwsum,
                                                     int* __restrict__ deg,
                                                     float* __restrict__ wsum,
                                                     int* __restrict__ bsum) {
  int node = blockIdx.x * 256 + threadIdx.x;
  int acc = 0; float wacc = 0.f;
  if (node < NN) {
    for (int c = 0; c < CC; ++c) {
      size_t idx = (size_t)c * NN + node;
      int t = pdeg[idx];
      pdeg[idx] = acc;        // exclusive prefix over chunks
      acc += t;
      wacc += pwsum[idx];
    }
    deg[node] = acc;          // real degree
    wsum[node] = wacc;
  }
  __shared__ int red[256];
  red[threadIdx.x] = (node < NN) ? ((acc + 7) & ~7) : 0;   // padded degree
  __syncthreads();
  for (int off = 128; off > 0; off >>= 1) {
    if (threadIdx.x < off) red[threadIdx.x] += red[threadIdx.x + off];
    __syncthreads();
  }
  if (threadIdx.x == 0) bsum[blockIdx.x] = red[0];
}

__global__ __launch_bounds__(256) void scan2_kernel(const int* __restrict__ bsum,
                                                    int* __restrict__ boff,
                                                    int* __restrict__ row_start, int nb, int n) {
  __shared__ int buf[256];
  int tid = threadIdx.x;
  int v = (tid < nb) ? bsum[tid] : 0;
  buf[tid] = v;
  __syncthreads();
  for (int off = 1; off < 256; off <<= 1) {
    int t = (tid >= off) ? buf[tid - off] : 0;
    __syncthreads();
    buf[tid] += t;
    __syncthreads();
  }
  if (tid < nb) boff[tid] = buf[tid] - v;  // exclusive prefix
  if (tid == 255) row_start[n] = buf[255];
}

// scan over PADDED degrees -> row_start
__global__ __launch_bounds__(256) void scan3_kernel(const int* __restrict__ deg,
                                                    const int* __restrict__ boff,
                                                    int* __restrict__ row_start, int n) {
  __shared__ int buf[256];
  int tid = threadIdx.x;
  int i = blockIdx.x * 256 + tid;
  int v = (i < n) ? ((deg[i] + 7) & ~7) : 0;
  buf[tid] = v;
  __syncthreads();
  for (int off = 1; off < 256; off <<= 1) {
    int t = (tid >= off) ? buf[tid - off] : 0;
    __syncthreads();
    buf[tid] += t;
    __syncthreads();
  }
  if (i < n) row_start[i] = boff[blockIdx.x] + buf[tid] - v;
}

__global__ __launch_bounds__(256) void csr_fill_kernel(const int* __restrict__ ei,
                                                       const float* __restrict__ ew,
                                                       const float* __restrict__ wsum,
                                                       const int* __restrict__ row_start,
                                                       const int* __restrict__ pdeg_excl,
                                                       const int* __restrict__ rank,
                                                       int2* __restrict__ csr, int e_cnt) {
  int e = blockIdx.x * 256 + threadIdx.x;
  if (e >= e_cnt) return;
  int c = e / CH;
  int src = ei[e], dst = ei[EE + e];
  float ws = wsum[src];
  ws = ws < 1.f ? 1.f : ws;
  float v = 0.9f * ew[e] / ws;            // (1-ALPHA) * enorm folded together
  int pos = row_start[dst] + pdeg_excl[(size_t)c * NN + dst] + rank[e];
  csr[pos] = make_int2(src, __float_as_int(v));
}

// fill pad slots [row_start+deg, row_start_next) with (src=0, w=+0.f): contributes 0.
__global__ __launch_bounds__(256) void pad_fill_kernel(const int* __restrict__ deg,
                                                       const int* __restrict__ row_start,
                                                       long* __restrict__ csr) {
  int node = blockIdx.x * 256 + threadIdx.x;
  if (node >= NN) return;
  int s = row_start[node] + deg[node];
  int e = row_start[node + 1];
  for (int i = s; i < e; ++i) csr[i] = 0;
}

// ---------------- propagation: one wave per 2 consecutive nodes, fp16 h ----------------
// CSR rows padded to multiples of 8 -> tail-free. Two consecutive nodes have CONTIGUOUS
// CSR segments; one pipelined 8-edge batch stream covers both; wave-uniform flag selects
// the accumulator. (R2-proven version — per-dispatch loop; fused/coop variants measured
// WORSE: R3 plane-split 2x slower, R5 fence-barrier 5x slower from L2-invalidate storms.)
__device__ __forceinline__ void prop_pair(int nA, int lane,
                                          const __half2* __restrict__ hc,
                                          const __half2* __restrict__ bp,
                                          const int* __restrict__ row_start,
                                          const long* __restrict__ csr,
                                          __half2* __restrict__ np) {
  int nB = nA + 1;
  float2 vbA = __half22float2(bp[(size_t)nA * 64 + lane]);
  float2 vbB = __half22float2(bp[(size_t)nB * 64 + lane]);
  float aAx = 0.1f * vbA.x, aAy = 0.1f * vbA.y, bAx = 0.f, bAy = 0.f;
  float aBx = 0.1f * vbB.x, aBy = 0.1f * vbB.y, bBx = 0.f, bBy = 0.f;
  int s  = __builtin_amdgcn_readfirstlane(row_start[nA]);
  int eA = __builtin_amdgcn_readfirstlane(row_start[nA + 1]);
  int eB = __builtin_amdgcn_readfirstlane(row_start[nB + 1]);
  int nb = (eB - s) >> 3;          // all batches full (padded)
  int i = s;
  if (nb > 0) {
    long cur[8];
    bool curB = (i >= eA);
#pragma unroll
    for (int j = 0; j < 8; ++j) cur[j] = csr[i + j];
    i += 8;
    for (int bidx = 1; bidx < nb; ++bidx) {
      long nxt[8];
      bool nxtB = (i >= eA);
#pragma unroll
      for (int j = 0; j < 8; ++j) nxt[j] = csr[i + j];
      i += 8;
      float2 g[8];
#pragma unroll
      for (int j = 0; j < 8; ++j) g[j] = __half22float2(hc[(size_t)(int)cur[j] * 64 + lane]);
      if (curB) {
#pragma unroll
        for (int j = 0; j < 8; ++j) {
          float v = __int_as_float((int)(cur[j] >> 32));
          if (j & 1) { bBx = fmaf(v, g[j].x, bBx); bBy = fmaf(v, g[j].y, bBy); }
          else       { aBx = fmaf(v, g[j].x, aBx); aBy = fmaf(v, g[j].y, aBy); }
        }
      } else {
#pragma unroll
        for (int j = 0; j < 8; ++j) {
          float v = __int_as_float((int)(cur[j] >> 32));
          if (j & 1) { bAx = fmaf(v, g[j].x, bAx); bAy = fmaf(v, g[j].y, bAy); }
          else       { aAx = fmaf(v, g[j].x, aAx); aAy = fmaf(v, g[j].y, aAy); }
        }
      }
#pragma unroll
      for (int j = 0; j < 8; ++j) cur[j] = nxt[j];
      curB = nxtB;
    }
    float2 g[8];
#pragma unroll
    for (int j = 0; j < 8; ++j) g[j] = __half22float2(hc[(size_t)(int)cur[j] * 64 + lane]);
    if (curB) {
#pragma unroll
      for (int j = 0; j < 8; ++j) {
        float v = __int_as_float((int)(cur[j] >> 32));
        if (j & 1) { bBx = fmaf(v, g[j].x, bBx); bBy = fmaf(v, g[j].y, bBy); }
        else       { aBx = fmaf(v, g[j].x, aBx); aBy = fmaf(v, g[j].y, aBy); }
      }
    } else {
#pragma unroll
      for (int j = 0; j < 8; ++j) {
        float v = __int_as_float((int)(cur[j] >> 32));
        if (j & 1) { bAx = fmaf(v, g[j].x, bAx); bAy = fmaf(v, g[j].y, bAy); }
        else       { aAx = fmaf(v, g[j].x, aAx); aAy = fmaf(v, g[j].y, aAy); }
      }
    }
  }
  np[(size_t)nA * 64 + lane] = __float22half2_rn(make_float2(aAx + bAx, aAy + bAy));
  np[(size_t)nB * 64 + lane] = __float22half2_rn(make_float2(aBx + bBx, aBy + bBy));
}

__global__ __launch_bounds__(256, 6) void prop_kernel(const __half* __restrict__ h_cur,
                                                      const __half* __restrict__ base,
                                                      const int* __restrict__ row_start,
                                                      const long* __restrict__ csr,
                                                      __half* __restrict__ h_next) {
  int pair = __builtin_amdgcn_readfirstlane((int)blockIdx.x * 4 + (int)(threadIdx.x >> 6));
  if (pair * 2 >= NN) return;
  prop_pair(pair * 2, threadIdx.x & 63, (const __half2*)h_cur, (const __half2*)base,
            row_start, csr, (__half2*)h_next);
}

// ---------------- MFMA dense v2: out[n][j] = act(sum_k X[n][k] * W[j][k] + ...) ----------
// One 16-row tile per wave. X rows wave-private -> A-fragments direct from global; only W
// staged in LDS (fp16, XOR-swizzled).
// FG variant: A-fragment computed on the fly as sum_k attw[row][k] * XS_k[row][c..c+8]
//   (fp32 accum, fp16 convert — bit-identical to the old fused_gather->head1 pipeline).
// ATT2 variant (att1 only, JP=64): epilogue stages the fp16-rounded gelu outputs in LDS
//   (reusing wL after a barrier), then 64 threads compute att2 (11x64) + softmax and
//   write attw directly — bit-identical inputs to the old att2_softmax kernel.
template <int K, int KA, int JP, int JR, int ACT, bool RESID, typename IT, typename OT,
          bool FG = false, bool ATT2 = false>
__global__ __launch_bounds__(256) void mfma_dense2(
    const IT* __restrict__ Xa, const IT* __restrict__ Xb,
    const float* __restrict__ W, const float* __restrict__ lb,
    const float* __restrict__ bg, const float* __restrict__ bb,
    const float* __restrict__ bm, const float* __restrict__ bv,
    const OT* __restrict__ resid, OT* __restrict__ out,
    const float* __restrict__ attwp = nullptr,
    const float* __restrict__ W2 = nullptr,
    const float* __restrict__ b2 = nullptr,
    float* __restrict__ attw_out = nullptr) {
  static_assert(K % 32 == 0 && KA % 32 == 0 && JP % 16 == 0, "");
  constexpr int JT = JP / 16;      // 16-col MFMA tiles
  constexpr int NS = K / 32;       // K-slices of 32
  constexpr bool ISF = __is_same(IT, float);
  __shared__ _Float16 wL[JP][K];   // swizzled: 16B chunk c stored at chunk (c ^ (j&7))
  static_assert(!ATT2 || (JP == 64 && JR == 64 && sizeof(wL) >= 64 * 65 * 4), "");

  const int tid = threadIdx.x;
  const int wv = tid >> 6, lane = tid & 63;
  const int q = lane >> 4, m = lane & 15;
  const int t = blockIdx.x * 4 + wv;           // tile id (16 rows)
  const bool active = (t < NN / 16);
  const int row = t * 16 + m;

  // ---- issue per-lane A-fragment loads (direct global, 16B each) ----
  half8  a[ISF ? 1 : NS];
  float4 af0[ISF ? NS : 1], af1[ISF ? NS : 1];
  float awr[FG ? 12 : 1];
  if (active) {
    if constexpr (FG) {
      *(float4*)&awr[0] = *(const float4*)&attwp[row * 16 + 0];
      *(float4*)&awr[4] = *(const float4*)&attwp[row * 16 + 4];
      *(float4*)&awr[8] = *(const float4*)&attwp[row * 16 + 8];
    } else {
#pragma unroll
      for (int s = 0; s < NS; ++s) {
        int c = s * 32 + q * 8;
        if constexpr (ISF) {
          const float* p = (const float*)Xa + (size_t)row * K + c;
          af0[s] = *(const float4*)p;
          af1[s] = *(const float4*)(p + 4);
        } else {
          const __half* p = (c < KA) ? (const __half*)Xa + (size_t)row * KA + c
                                     : (const __half*)Xb + (size_t)row * (K - KA) + (c - KA);
          a[s] = *(const half8*)p;
        }
      }
    }
  }

  // ---- stage W: fp32 -> fp16, swizzled LDS; zero-fill rows j >= JR ----
  constexpr int C4 = K / 4;
  for (int idx = tid; idx < JP * C4; idx += 256) {
    int j = idx / C4;
    int c4 = (idx % C4) * 4;
    float4 v = make_float4(0.f, 0.f, 0.f, 0.f);
    if (j < JR) v = *(const float4*)&W[(size_t)j * K + c4];
    int cs = ((((c4 >> 3) ^ (j & 7)) << 3) | (c4 & 7));
    *(half4v*)&wL[j][cs] = (half4v){(_Float16)v.x, (_Float16)v.y,
                                    (_Float16)v.z, (_Float16)v.w};
  }
  __syncthreads();

  if constexpr (!ATT2) {
    if (!active) return;
  }

  floatx4 acc[JT];
#pragma unroll
  for (int jt = 0; jt < JT; ++jt) acc[jt] = (floatx4)(0.f);

  if (active) {
#pragma unroll
    for (int s = 0; s < NS; ++s) {
      half8 av;
      if constexpr (FG) {
        float f[8] = {0.f, 0.f, 0.f, 0.f, 0.f, 0.f, 0.f, 0.f};
        const __half* bptr = (const __half*)Xa + (size_t)row * K + (s * 32 + q * 8);
#pragma unroll
        for (int k = 0; k <= KIT; ++k) {
          half8 v = *(const half8*)(bptr + (size_t)k * NHF);
#pragma unroll
          for (int e = 0; e < 8; ++e) f[e] = fmaf(awr[k], (float)v[e], f[e]);
        }
        av = (half8){(_Float16)f[0], (_Float16)f[1], (_Float16)f[2], (_Float16)f[3],
                     (_Float16)f[4], (_Float16)f[5], (_Float16)f[6], (_Float16)f[7]};
      } else if constexpr (ISF) {
        float4 f0 = af0[s], f1 = af1[s];
        av = (half8){(_Float16)f0.x, (_Float16)f0.y, (_Float16)f0.z, (_Float16)f0.w,
                     (_Float16)f1.x, (_Float16)f1.y, (_Float16)f1.z, (_Float16)f1.w};
      } else {
        av = a[s];
      }
      int kq = s * 4 + q;                        // 16B chunk index within row
#pragma unroll
      for (int jt = 0; jt < JT; ++jt) {
        int j = jt * 16 + m;
        half8 b = *(const half8*)&wL[j][(kq ^ (j & 7)) << 3];
        acc[jt] = __builtin_amdgcn_mfma_f32_16x16x32_f16(av, b, acc[jt], 0, 0, 0);
      }
    }
  }

  if constexpr (ATT2) {
    // ---- fused att2 + softmax (att1 instantiation only) ----
    float* attL = (float*)&wL[0][0];   // reuse wL (32KB >= 64*65*4B) after barrier
    __syncthreads();                   // all waves done reading wL
    if (active) {
#pragma unroll
      for (int jt = 0; jt < JT; ++jt) {
        int j = jt * 16 + m;
        float sh = lb[j];
#pragma unroll
        for (int reg = 0; reg < 4; ++reg) {
          float y = gelu_exact(acc[jt][reg] + sh);
          // fp16 round-trip: bit-identical to old gbuf(fp16) -> att2 path
          y = __half2float(__float2half_rn(y));
          attL[(wv * 16 + q * 4 + reg) * 65 + j] = y;
        }
      }
    }
    __syncthreads();
    if (tid < 64) {
      int n = blockIdx.x * 64 + tid;
      if (n < NN) {
        float a2[KIT + 1];
#pragma unroll
        for (int j = 0; j < KIT + 1; ++j) {
          float acc2 = b2[j];
#pragma unroll
          for (int k = 0; k < 64; ++k) acc2 = fmaf(attL[tid * 65 + k], W2[j * 64 + k], acc2);
          a2[j] = acc2;
        }
        float mx = a2[0];
#pragma unroll
        for (int j = 1; j < KIT + 1; ++j) mx = fmaxf(mx, a2[j]);
        float ssum = 0.f;
#pragma unroll
        for (int j = 0; j < KIT + 1; ++j) { a2[j] = expf(a2[j] - mx); ssum += a2[j]; }
        float inv = 1.f / ssum;
#pragma unroll
        for (int j = 0; j < KIT + 1; ++j) attw_out[n * 16 + j] = a2[j] * inv;
      }
    }
    return;
  }

  // epilogue: lane holds col j = jt*16 + m, rows q*4 + reg
#pragma unroll
  for (int jt = 0; jt < JT; ++jt) {
    int j = jt * 16 + m;
    if (j >= JR) continue;
    float sc = 0.f, sh;
    if (ACT == 1) {
      sc = bg[j] * rsqrtf(bv[j] + 1e-5f);
      sh = (lb[j] - bm[j]) * sc + bb[j];
    } else {
      sh = lb[j];
    }
#pragma unroll
    for (int reg = 0; reg < 4; ++reg) {
      int r = t * 16 + q * 4 + reg;
      float aa = acc[jt][reg];
      float y;
      if (ACT == 0)      y = aa + sh;
      else if (ACT == 1) y = fmaxf(fmaf(aa, sc, sh), 0.f);
      else               y = gelu_exact(aa + sh);
      if (RESID) y += (float)resid[(size_t)r * JR + j];
      st1(&out[(size_t)r * JR + j], y);
    }
  }
}

// recompute-path variant: fused (+)= attw[:,k] * h (h fp16, fused fp32 for accumulation)
__global__ __launch_bounds__(256) void fused_accum_kernel(const __half* __restrict__ h,
                                                          const float* __restrict__ attw,
                                                          float* __restrict__ fused, int k) {
  int node = __builtin_amdgcn_readfirstlane((int)blockIdx.x * 4 + (int)(threadIdx.x >> 6));
  if (node >= NN) return;
  int lane = threadIdx.x & 63;
  float wk = attw[node * 16 + k];
  float2 v = __half22float2(((const __half2*)h)[(size_t)node * 64 + lane]);
  float2 o;
  if (k == 0) {
    o = make_float2(wk * v.x, wk * v.y);
  } else {
    float2 f = ((const float2*)fused)[(size_t)node * 64 + lane];
    o = make_float2(fmaf(wk, v.x, f.x), fmaf(wk, v.y, f.y));
  }
  ((float2*)fused)[(size_t)node * 64 + lane] = o;
}

extern "C" void kernel_launch(void* const* d_in, const int* in_sizes, int n_in,
                              void* d_out, int out_size, void* d_ws, size_t ws_size,
                              hipStream_t stream) {
  (void)in_sizes; (void)n_in; (void)out_size;
  const float* x      = (const float*)d_in[0];
  const int*   ei     = (const int*)d_in[1];
  const float* ew     = (const float*)d_in[2];
  const float* lin1_w = (const float*)d_in[3];
  const float* lin1_b = (const float*)d_in[4];
  const float* bn1_g  = (const float*)d_in[5];
  const float* bn1_b  = (const float*)d_in[6];
  const float* bn1_m  = (const float*)d_in[7];
  const float* bn1_v  = (const float*)d_in[8];
  const float* lin2_w = (const float*)d_in[9];
  const float* lin2_b = (const float*)d_in[10];
  const float* bn2_g  = (const float*)d_in[11];
  const float* bn2_b  = (const float*)d_in[12];
  const float* bn2_m  = (const float*)d_in[13];
  const float* bn2_v  = (const float*)d_in[14];
  const float* att1_w = (const float*)d_in[15];
  const float* att1_b = (const float*)d_in[16];
  const float* att2_w = (const float*)d_in[17];
  const float* att2_b = (const float*)d_in[18];
  const float* head1_w= (const float*)d_in[19];
  const float* head1_b= (const float*)d_in[20];
  const float* bn3_g  = (const float*)d_in[21];
  const float* bn3_b  = (const float*)d_in[22];
  const float* bn3_m  = (const float*)d_in[23];
  const float* bn3_v  = (const float*)d_in[24];
  const float* head2_w= (const float*)d_in[25];
  const float* head2_b= (const float*)d_in[26];
  float* out = (float*)d_out;

  char* p = (char*)d_ws;
  auto alloc = [&](size_t bytes) -> void* {
    void* r = (void*)p;
    p += (bytes + 255) & ~(size_t)255;
    return r;
  };
  // persistent buffers (live across whole launch)
  int*   row_start= (int*)alloc((size_t)(NN + 1) * 4);
  int*   bsum     = (int*)alloc((size_t)256 * 4);
  int*   boff     = (int*)alloc((size_t)256 * 4);
  int*   deg      = (int*)alloc((size_t)NN * 4);
  float* wsum     = (float*)alloc((size_t)NN * 4);
  long*  csr      = (long*)alloc(((size_t)EE + 8 * NN) * 8);  // padded rows (<=7/node)
  float* attw     = (float*)alloc((size_t)NN * 16 * 4);
  __half* h1      = (__half*)alloc((size_t)NHF * 2);
  __half* zbuf    = (__half*)alloc((size_t)NN * 64 * 2);
  size_t common = (size_t)(p - (char*)d_ws);
  size_t stored_need = common + (size_t)(KIT + 1) * NHF * 2 + 4096;
  bool stored = ws_size >= stored_need;

  // preprocessing temporaries overlay XS[8..10] (dead until prop k=7) in stored path.
  __half* XS = nullptr;
  int* pdeg; float* pwsum; int* rank;
  if (stored) {
    XS = (__half*)alloc((size_t)(KIT + 1) * NHF * 2);
    char* ovl = (char*)(XS + (size_t)8 * NHF);
    pdeg  = (int*)ovl;
    pwsum = (float*)(ovl + (size_t)CC * NN * 4);
    rank  = (int*)(ovl + 2 * (size_t)CC * NN * 4);
  } else {
    pdeg  = (int*)alloc((size_t)CC * NN * 4);
    pwsum = (float*)alloc((size_t)CC * NN * 4);
    rank  = (int*)alloc((size_t)EE * 4);
  }

  const int GE  = (EE + 255) / 256;          // edge-parallel grid
  const int GN  = (NN + 255) / 256;          // node-parallel grid (196)
  const int GT  = (NN / 16 + 3) / 4;         // dense v2 grid: 3125 wave-tiles -> 782 blocks
  const int GP  = (NN + 3) / 4;              // wave-per-node grids (12500)
  const int GP2 = (NN / 2 + 3) / 4;          // wave-per-2-nodes prop grid (6250)

  // graph preprocessing (atomic-free)
  hist2_kernel<<<dim3(CC, 2 * RRH), 256, 0, stream>>>(ei, ew, pdeg, pwsum, rank);
  reduce_kernel<<<GN, 256, 0, stream>>>(pdeg, pwsum, deg, wsum, bsum);
  scan2_kernel<<<1, 256, 0, stream>>>(bsum, boff, row_start, GN, NN);
  scan3_kernel<<<GN, 256, 0, stream>>>(deg, boff, row_start, NN);
  csr_fill_kernel<<<GE, 256, 0, stream>>>(ei, ew, wsum, row_start, pdeg, rank,
                                          (int2*)csr, EE);
  pad_fill_kernel<<<GN, 256, 0, stream>>>(deg, row_start, csr);

  if (stored) {
    mfma_dense2<128, 128, 128, 128, 1, false, float, __half><<<GT, 256, 0, stream>>>(
        x, (const float*)nullptr, lin1_w, lin1_b, bn1_g, bn1_b, bn1_m, bn1_v, nullptr, h1);
    mfma_dense2<128, 128, 128, 128, 1, true, __half, __half><<<GT, 256, 0, stream>>>(
        h1, (const __half*)nullptr, lin2_w, lin2_b, bn2_g, bn2_b, bn2_m, bn2_v, h1, XS);
    for (int k = 0; k < KIT; ++k) {
      prop_kernel<<<GP2, 256, 0, stream>>>(XS + (size_t)k * NHF, XS, row_start,
                                           csr, XS + (size_t)(k + 1) * NHF);
    }
    // att1 with fused att2 + softmax (writes attw directly)
    mfma_dense2<256, 128, 64, 64, 2, false, __half, __half, false, true>
        <<<GT, 256, 0, stream>>>(
        XS, XS + (size_t)KIT * NHF, att1_w, att1_b, nullptr, nullptr, nullptr, nullptr,
        nullptr, (__half*)nullptr, nullptr, att2_w, att2_b, attw);
    // head1 with inline attention-fusion of the 11 snapshots (FG=true)
    mfma_dense2<128, 128, 64, 64, 1, false, __half, __half, true><<<GT, 256, 0, stream>>>(
        XS, (const __half*)nullptr, head1_w, head1_b, bn3_g, bn3_b, bn3_m, bn3_v,
        nullptr, zbuf, attw);
  } else {
    float*  fusedF = (float*)alloc((size_t)NHF * 4);
    __half* base   = (__half*)alloc((size_t)NHF * 2);
    __half* hA     = (__half*)alloc((size_t)NHF * 2);
    __half* hB     = (__half*)alloc((size_t)NHF * 2);
    mfma_dense2<128, 128, 128, 128, 1, false, float, __half><<<GT, 256, 0, stream>>>(
        x, (const float*)nullptr, lin1_w, lin1_b, bn1_g, bn1_b, bn1_m, bn1_v, nullptr, h1);
    mfma_dense2<128, 128, 128, 128, 1, true, __half, __half><<<GT, 256, 0, stream>>>(
        h1, (const __half*)nullptr, lin2_w, lin2_b, bn2_g, bn2_b, bn2_m, bn2_v, h1, base);
    // pass 1: get xs10
    const __half* cur = base;
    for (int k = 1; k <= KIT; ++k) {
      __half* nxt = (k & 1) ? hA : hB;
      prop_kernel<<<GP2, 256, 0, stream>>>(cur, base, row_start, csr, nxt);
      cur = nxt;
    }
    mfma_dense2<256, 128, 64, 64, 2, false, __half, __half, false, true>
        <<<GT, 256, 0, stream>>>(
        base, cur, att1_w, att1_b, nullptr, nullptr, nullptr, nullptr,
        nullptr, (__half*)nullptr, nullptr, att2_w, att2_b, attw);
    // pass 2: re-propagate, accumulate fused on the fly (fp32 accumulator)
    fused_accum_kernel<<<GP, 256, 0, stream>>>(base, attw, fusedF, 0);
    cur = base;
    for (int k = 1; k <= KIT; ++k) {
      __half* nxt = (k & 1) ? hA : hB;
      prop_kernel<<<GP2, 256, 0, stream>>>(cur, base, row_start, csr, nxt);
      fused_accum_kernel<<<GP, 256, 0, stream>>>(nxt, attw, fusedF, k);
      cur = nxt;
    }
    mfma_dense2<128, 128, 64, 64, 1, false, float, __half><<<GT, 256, 0, stream>>>(
        fusedF, (const float*)nullptr, head1_w, head1_b, bn3_g, bn3_b, bn3_m, bn3_v,
        nullptr, zbuf);
  }

  // head2 (z fp16 -> out fp32)
  mfma_dense2<64, 64, 48, 40, 0, false, __half, float><<<GT, 256, 0, stream>>>(
      zbuf, (const __half*)nullptr, head2_w, head2_b, nullptr, nullptr, nullptr, nullptr,
      nullptr, out);
}

// Round 7
// 542.582 us; speedup vs baseline: 3.5794x; 1.0429x over previous
//
#include <hip/hip_runtime.h>
#include <hip/hip_fp16.h>
#include <math.h>

#define NN 50000
#define EE 800000
#define HH 128
#define KIT 10
#define NHF (NN * HH)     // 6,400,000 elements per snapshot
#define CC 64             // edge chunks
#define CH 12500          // edges per chunk (divisible by 4; byte offset 16B-aligned)
#define RRH 4             // node ranges per mode
#define NRH 12500         // nodes per range (50KB LDS)

typedef _Float16 half8 __attribute__((ext_vector_type(8)));
typedef _Float16 half4v __attribute__((ext_vector_type(4)));
typedef float floatx4 __attribute__((ext_vector_type(4)));

static_assert(NN % 16 == 0, "row tiles must be exact");

__device__ __forceinline__ float gelu_exact(float x) {
  return 0.5f * x * (1.f + erff(x * 0.70710678118654752f));
}

// typed 4-float load/store helpers (fp32 or fp16 storage)
__device__ __forceinline__ float4 ld4(const float* p) { return *(const float4*)p; }
__device__ __forceinline__ float4 ld4(const __half* p) {
  const __half2* q = (const __half2*)p;
  float2 lo = __half22float2(q[0]);
  float2 hi = __half22float2(q[1]);
  return make_float4(lo.x, lo.y, hi.x, hi.y);
}
__device__ __forceinline__ void st1(float* p, float v) { *p = v; }
__device__ __forceinline__ void st1(__half* p, float v) { *p = __float2half_rn(v); }

// ---------------- graph preprocessing (NO global atomics) ----------------
__global__ __launch_bounds__(256) void hist2_kernel(const int* __restrict__ ei,
                                                    const float* __restrict__ ew,
                                                    int* __restrict__ pdeg,
                                                    float* __restrict__ pwsum,
                                                    int* __restrict__ rank) {
  __shared__ int hist[NRH];
  const int c = blockIdx.x;
  const int z = blockIdx.y;
  const bool isdeg = (z < RRH);
  const int lo = (isdeg ? z : z - RRH) * NRH;
  for (int i = threadIdx.x; i < NRH; i += 256) hist[i] = 0;   // 0 bits == 0.f
  __syncthreads();
  const int e0 = c * CH;
  if (isdeg) {
    const int4* d4 = (const int4*)(ei + (size_t)EE + e0);
    for (int i = threadIdx.x; i < CH / 4; i += 256) {
      int4 d = d4[i];
      int e = e0 + i * 4;
      unsigned u0 = (unsigned)(d.x - lo), u1 = (unsigned)(d.y - lo);
      unsigned u2 = (unsigned)(d.z - lo), u3 = (unsigned)(d.w - lo);
      if (u0 < NRH) rank[e]     = atomicAdd(&hist[u0], 1);
      if (u1 < NRH) rank[e + 1] = atomicAdd(&hist[u1], 1);
      if (u2 < NRH) rank[e + 2] = atomicAdd(&hist[u2], 1);
      if (u3 < NRH) rank[e + 3] = atomicAdd(&hist[u3], 1);
    }
    __syncthreads();
    for (int i = threadIdx.x; i < NRH; i += 256)
      pdeg[(size_t)c * NN + lo + i] = hist[i];
  } else {
    float* whist = (float*)hist;
    const int4* s4 = (const int4*)(ei + e0);
    const float4* w4 = (const float4*)(ew + e0);
    for (int i = threadIdx.x; i < CH / 4; i += 256) {
      int4 s = s4[i];
      float4 w = w4[i];
      unsigned u0 = (unsigned)(s.x - lo), u1 = (unsigned)(s.y - lo);
      unsigned u2 = (unsigned)(s.z - lo), u3 = (unsigned)(s.w - lo);
      if (u0 < NRH) atomicAdd(&whist[u0], w.x);
      if (u1 < NRH) atomicAdd(&whist[u1], w.y);
      if (u2 < NRH) atomicAdd(&whist[u2], w.z);
      if (u3 < NRH) atomicAdd(&whist[u3], w.w);
    }
    __syncthreads();
    for (int i = threadIdx.x; i < NRH; i += 256)
      pwsum[(size_t)c * NN + lo + i] = whist[i];
  }
}

// per-node: deg = sum over chunks (pdeg -> in-place exclusive chunk prefix),
// wsum = sum over chunks; block-reduce PADDED deg -> bsum (rows padded to mult of 8).
__global__ __launch_bounds__(256) void reduce_kernel(int* __restrict__ pdeg,
                                                     const float* __restrict__ pwsum,
                                                     int* __restrict__ deg,
                                                     float* __restrict__ wsum,
                                                     int* __restrict__ bsum) {
  int node = blockIdx.x * 256 + threadIdx.x;
  int acc = 0; float wacc = 0.f;
  if (node < NN) {
    for (int c = 0; c < CC; ++c) {
      size_t idx = (size_t)c * NN + node;
      int t = pdeg[idx];
      pdeg[idx] = acc;        // exclusive prefix over chunks
      acc += t;
      wacc += pwsum[idx];
    }
    deg[node] = acc;          // real degree
    wsum[node] = wacc;
  }
  __shared__ int red[256];
  red[threadIdx.x] = (node < NN) ? ((acc + 7) & ~7) : 0;   // padded degree
  __syncthreads();
  for (int off = 128; off > 0; off >>= 1) {
    if (threadIdx.x < off) red[threadIdx.x] += red[threadIdx.x + off];
    __syncthreads();
  }
  if (threadIdx.x == 0) bsum[blockIdx.x] = red[0];
}

__global__ __launch_bounds__(256) void scan2_kernel(const int* __restrict__ bsum,
                                                    int* __restrict__ boff,
                                                    int* __restrict__ row_start, int nb, int n) {
  __shared__ int buf[256];
  int tid = threadIdx.x;
  int v = (tid < nb) ? bsum[tid] : 0;
  buf[tid] = v;
  __syncthreads();
  for (int off = 1; off < 256; off <<= 1) {
    int t = (tid >= off) ? buf[tid - off] : 0;
    __syncthreads();
    buf[tid] += t;
    __syncthreads();
  }
  if (tid < nb) boff[tid] = buf[tid] - v;  // exclusive prefix
  if (tid == 255) row_start[n] = buf[255];
}

// scan over PADDED degrees -> row_start
__global__ __launch_bounds__(256) void scan3_kernel(const int* __restrict__ deg,
                                                    const int* __restrict__ boff,
                                                    int* __restrict__ row_start, int n) {
  __shared__ int buf[256];
  int tid = threadIdx.x;
  int i = blockIdx.x * 256 + tid;
  int v = (i < n) ? ((deg[i] + 7) & ~7) : 0;
  buf[tid] = v;
  __syncthreads();
  for (int off = 1; off < 256; off <<= 1) {
    int t = (tid >= off) ? buf[tid - off] : 0;
    __syncthreads();
    buf[tid] += t;
    __syncthreads();
  }
  if (i < n) row_start[i] = boff[blockIdx.x] + buf[tid] - v;
}

__global__ __launch_bounds__(256) void csr_fill_kernel(const int* __restrict__ ei,
                                                       const float* __restrict__ ew,
                                                       const float* __restrict__ wsum,
                                                       const int* __restrict__ row_start,
                                                       const int* __restrict__ pdeg_excl,
                                                       const int* __restrict__ rank,
                                                       int2* __restrict__ csr, int e_cnt) {
  int e = blockIdx.x * 256 + threadIdx.x;
  if (e >= e_cnt) return;
  int c = e / CH;
  int src = ei[e], dst = ei[EE + e];
  float ws = wsum[src];
  ws = ws < 1.f ? 1.f : ws;
  float v = 0.9f * ew[e] / ws;            // (1-ALPHA) * enorm folded together
  int pos = row_start[dst] + pdeg_excl[(size_t)c * NN + dst] + rank[e];
  csr[pos] = make_int2(src, __float_as_int(v));
}

// fill pad slots [row_start+deg, row_start_next) with (src=0, w=+0.f): contributes 0.
__global__ __launch_bounds__(256) void pad_fill_kernel(const int* __restrict__ deg,
                                                       const int* __restrict__ row_start,
                                                       long* __restrict__ csr) {
  int node = blockIdx.x * 256 + threadIdx.x;
  if (node >= NN) return;
  int s = row_start[node] + deg[node];
  int e = row_start[node + 1];
  for (int i = s; i < e; ++i) csr[i] = 0;
}

// ---------------- propagation: one wave per 2 consecutive nodes, fp16 h ----------------
// CSR rows padded to multiples of 8 -> tail-free. Two consecutive nodes have CONTIGUOUS
// CSR segments; one pipelined 8-edge batch stream covers both; wave-uniform flag selects
// the accumulator. (R2-proven version — per-dispatch loop; fused/coop variants measured
// WORSE: R3 plane-split 2x slower, R5 fence-barrier 5x slower from L2-invalidate storms.)
__device__ __forceinline__ void prop_pair(int nA, int lane,
                                          const __half2* __restrict__ hc,
                                          const __half2* __restrict__ bp,
                                          const int* __restrict__ row_start,
                                          const long* __restrict__ csr,
                                          __half2* __restrict__ np) {
  int nB = nA + 1;
  float2 vbA = __half22float2(bp[(size_t)nA * 64 + lane]);
  float2 vbB = __half22float2(bp[(size_t)nB * 64 + lane]);
  float aAx = 0.1f * vbA.x, aAy = 0.1f * vbA.y, bAx = 0.f, bAy = 0.f;
  float aBx = 0.1f * vbB.x, aBy = 0.1f * vbB.y, bBx = 0.f, bBy = 0.f;
  int s  = __builtin_amdgcn_readfirstlane(row_start[nA]);
  int eA = __builtin_amdgcn_readfirstlane(row_start[nA + 1]);
  int eB = __builtin_amdgcn_readfirstlane(row_start[nB + 1]);
  int nb = (eB - s) >> 3;          // all batches full (padded)
  int i = s;
  if (nb > 0) {
    long cur[8];
    bool curB = (i >= eA);
#pragma unroll
    for (int j = 0; j < 8; ++j) cur[j] = csr[i + j];
    i += 8;
    for (int bidx = 1; bidx < nb; ++bidx) {
      long nxt[8];
      bool nxtB = (i >= eA);
#pragma unroll
      for (int j = 0; j < 8; ++j) nxt[j] = csr[i + j];
      i += 8;
      float2 g[8];
#pragma unroll
      for (int j = 0; j < 8; ++j) g[j] = __half22float2(hc[(size_t)(int)cur[j] * 64 + lane]);
      if (curB) {
#pragma unroll
        for (int j = 0; j < 8; ++j) {
          float v = __int_as_float((int)(cur[j] >> 32));
          if (j & 1) { bBx = fmaf(v, g[j].x, bBx); bBy = fmaf(v, g[j].y, bBy); }
          else       { aBx = fmaf(v, g[j].x, aBx); aBy = fmaf(v, g[j].y, aBy); }
        }
      } else {
#pragma unroll
        for (int j = 0; j < 8; ++j) {
          float v = __int_as_float((int)(cur[j] >> 32));
          if (j & 1) { bAx = fmaf(v, g[j].x, bAx); bAy = fmaf(v, g[j].y, bAy); }
          else       { aAx = fmaf(v, g[j].x, aAx); aAy = fmaf(v, g[j].y, aAy); }
        }
      }
#pragma unroll
      for (int j = 0; j < 8; ++j) cur[j] = nxt[j];
      curB = nxtB;
    }
    float2 g[8];
#pragma unroll
    for (int j = 0; j < 8; ++j) g[j] = __half22float2(hc[(size_t)(int)cur[j] * 64 + lane]);
    if (curB) {
#pragma unroll
      for (int j = 0; j < 8; ++j) {
        float v = __int_as_float((int)(cur[j] >> 32));
        if (j & 1) { bBx = fmaf(v, g[j].x, bBx); bBy = fmaf(v, g[j].y, bBy); }
        else       { aBx = fmaf(v, g[j].x, aBx); aBy = fmaf(v, g[j].y, aBy); }
      }
    } else {
#pragma unroll
      for (int j = 0; j < 8; ++j) {
        float v = __int_as_float((int)(cur[j] >> 32));
        if (j & 1) { bAx = fmaf(v, g[j].x, bAx); bAy = fmaf(v, g[j].y, bAy); }
        else       { aAx = fmaf(v, g[j].x, aAx); aAy = fmaf(v, g[j].y, aAy); }
      }
    }
  }
  np[(size_t)nA * 64 + lane] = __float22half2_rn(make_float2(aAx + bAx, aAy + bAy));
  np[(size_t)nB * 64 + lane] = __float22half2_rn(make_float2(aBx + bBx, aBy + bBy));
}

__global__ __launch_bounds__(256, 6) void prop_kernel(const __half* __restrict__ h_cur,
                                                      const __half* __restrict__ base,
                                                      const int* __restrict__ row_start,
                                                      const long* __restrict__ csr,
                                                      __half* __restrict__ h_next) {
  int pair = __builtin_amdgcn_readfirstlane((int)blockIdx.x * 4 + (int)(threadIdx.x >> 6));
  if (pair * 2 >= NN) return;
  prop_pair(pair * 2, threadIdx.x & 63, (const __half2*)h_cur, (const __half2*)base,
            row_start, csr, (__half2*)h_next);
}

// ---------------- MFMA dense v2: out[n][j] = act(sum_k X[n][k] * W[j][k] + ...) ----------
// One 16-row tile per wave. X rows wave-private -> A-fragments direct from global; only W
// staged in LDS (fp16, XOR-swizzled).
// ATT2 variant (att1 only, JP=64): epilogue stages the fp16-rounded gelu outputs in LDS
//   (reusing wL after a barrier), then 64 threads compute att2 (11x64) + softmax and
//   write attw directly — bit-identical inputs to the old att2_softmax kernel.
template <int K, int KA, int JP, int JR, int ACT, bool RESID, typename IT, typename OT,
          bool ATT2 = false>
__global__ __launch_bounds__(256) void mfma_dense2(
    const IT* __restrict__ Xa, const IT* __restrict__ Xb,
    const float* __restrict__ W, const float* __restrict__ lb,
    const float* __restrict__ bg, const float* __restrict__ bb,
    const float* __restrict__ bm, const float* __restrict__ bv,
    const OT* __restrict__ resid, OT* __restrict__ out,
    const float* __restrict__ W2 = nullptr,
    const float* __restrict__ b2 = nullptr,
    float* __restrict__ attw_out = nullptr) {
  static_assert(K % 32 == 0 && KA % 32 == 0 && JP % 16 == 0, "");
  constexpr int JT = JP / 16;      // 16-col MFMA tiles
  constexpr int NS = K / 32;       // K-slices of 32
  constexpr bool ISF = __is_same(IT, float);
  __shared__ _Float16 wL[JP][K];   // swizzled: 16B chunk c stored at chunk (c ^ (j&7))
  static_assert(!ATT2 || (JP == 64 && JR == 64 && sizeof(wL) >= 64 * 65 * 4), "");

  const int tid = threadIdx.x;
  const int wv = tid >> 6, lane = tid & 63;
  const int q = lane >> 4, m = lane & 15;
  const int t = blockIdx.x * 4 + wv;           // tile id (16 rows)
  const bool active = (t < NN / 16);
  const int row = t * 16 + m;

  // ---- issue per-lane A-fragment loads (direct global, 16B each) ----
  half8  a[ISF ? 1 : NS];
  float4 af0[ISF ? NS : 1], af1[ISF ? NS : 1];
  if (active) {
#pragma unroll
    for (int s = 0; s < NS; ++s) {
      int c = s * 32 + q * 8;
      if constexpr (ISF) {
        const float* p = (const float*)Xa + (size_t)row * K + c;
        af0[s] = *(const float4*)p;
        af1[s] = *(const float4*)(p + 4);
      } else {
        const __half* p = (c < KA) ? (const __half*)Xa + (size_t)row * KA + c
                                   : (const __half*)Xb + (size_t)row * (K - KA) + (c - KA);
        a[s] = *(const half8*)p;
      }
    }
  }

  // ---- stage W: fp32 -> fp16, swizzled LDS; zero-fill rows j >= JR ----
  constexpr int C4 = K / 4;
  for (int idx = tid; idx < JP * C4; idx += 256) {
    int j = idx / C4;
    int c4 = (idx % C4) * 4;
    float4 v = make_float4(0.f, 0.f, 0.f, 0.f);
    if (j < JR) v = *(const float4*)&W[(size_t)j * K + c4];
    int cs = ((((c4 >> 3) ^ (j & 7)) << 3) | (c4 & 7));
    *(half4v*)&wL[j][cs] = (half4v){(_Float16)v.x, (_Float16)v.y,
                                    (_Float16)v.z, (_Float16)v.w};
  }
  __syncthreads();

  if constexpr (!ATT2) {
    if (!active) return;
  }

  floatx4 acc[JT];
#pragma unroll
  for (int jt = 0; jt < JT; ++jt) acc[jt] = (floatx4)(0.f);

  if (active) {
#pragma unroll
    for (int s = 0; s < NS; ++s) {
      half8 av;
      if constexpr (ISF) {
        float4 f0 = af0[s], f1 = af1[s];
        av = (half8){(_Float16)f0.x, (_Float16)f0.y, (_Float16)f0.z, (_Float16)f0.w,
                     (_Float16)f1.x, (_Float16)f1.y, (_Float16)f1.z, (_Float16)f1.w};
      } else {
        av = a[s];
      }
      int kq = s * 4 + q;                        // 16B chunk index within row
#pragma unroll
      for (int jt = 0; jt < JT; ++jt) {
        int j = jt * 16 + m;
        half8 b = *(const half8*)&wL[j][(kq ^ (j & 7)) << 3];
        acc[jt] = __builtin_amdgcn_mfma_f32_16x16x32_f16(av, b, acc[jt], 0, 0, 0);
      }
    }
  }

  if constexpr (ATT2) {
    // ---- fused att2 + softmax (att1 instantiation only) ----
    float* attL = (float*)&wL[0][0];   // reuse wL (32KB >= 64*65*4B) after barrier
    __syncthreads();                   // all waves done reading wL
    if (active) {
#pragma unroll
      for (int jt = 0; jt < JT; ++jt) {
        int j = jt * 16 + m;
        float sh = lb[j];
#pragma unroll
        for (int reg = 0; reg < 4; ++reg) {
          float y = gelu_exact(acc[jt][reg] + sh);
          // fp16 round-trip: bit-identical to old gbuf(fp16) -> att2 path
          y = __half2float(__float2half_rn(y));
          attL[(wv * 16 + q * 4 + reg) * 65 + j] = y;
        }
      }
    }
    __syncthreads();
    if (tid < 64) {
      int n = blockIdx.x * 64 + tid;
      if (n < NN) {
        float a2[KIT + 1];
#pragma unroll
        for (int j = 0; j < KIT + 1; ++j) {
          float acc2 = b2[j];
#pragma unroll
          for (int k = 0; k < 64; ++k) acc2 = fmaf(attL[tid * 65 + k], W2[j * 64 + k], acc2);
          a2[j] = acc2;
        }
        float mx = a2[0];
#pragma unroll
        for (int j = 1; j < KIT + 1; ++j) mx = fmaxf(mx, a2[j]);
        float ssum = 0.f;
#pragma unroll
        for (int j = 0; j < KIT + 1; ++j) { a2[j] = expf(a2[j] - mx); ssum += a2[j]; }
        float inv = 1.f / ssum;
#pragma unroll
        for (int j = 0; j < KIT + 1; ++j) attw_out[n * 16 + j] = a2[j] * inv;
      }
    }
    return;
  }

  // epilogue: lane holds col j = jt*16 + m, rows q*4 + reg
#pragma unroll
  for (int jt = 0; jt < JT; ++jt) {
    int j = jt * 16 + m;
    if (j >= JR) continue;
    float sc = 0.f, sh;
    if (ACT == 1) {
      sc = bg[j] * rsqrtf(bv[j] + 1e-5f);
      sh = (lb[j] - bm[j]) * sc + bb[j];
    } else {
      sh = lb[j];
    }
#pragma unroll
    for (int reg = 0; reg < 4; ++reg) {
      int r = t * 16 + q * 4 + reg;
      float aa = acc[jt][reg];
      float y;
      if (ACT == 0)      y = aa + sh;
      else if (ACT == 1) y = fmaxf(fmaf(aa, sc, sh), 0.f);
      else               y = gelu_exact(aa + sh);
      if (RESID) y += (float)resid[(size_t)r * JR + j];
      st1(&out[(size_t)r * JR + j], y);
    }
  }
}

// ---------------- head1 with fused attention-gather (stored path) ----------------
// Per 64-row block: stage attw (4KB) + W (16KB swizzled) in LDS; cooperatively compute
// fused[row][d] = sum_k attw[row][k] * XS_k[row][d] with FULLY-COALESCED 16B/thread reads
// of each snapshot's contiguous 64x128 block (fp32 fmaf, k ascending, then fp16 round —
// bit-identical to the verified R6 FG arithmetic); MFMA reads A-fragments from LDS.
// Replaces R6's FG variant whose strided 11-stream fragment loads ran at 3.0 TB/s.
__global__ __launch_bounds__(256) void head1_fg_kernel(
    const __half* __restrict__ XS, const float* __restrict__ attw,
    const float* __restrict__ W, const float* __restrict__ lb,
    const float* __restrict__ bg, const float* __restrict__ bb,
    const float* __restrict__ bm, const float* __restrict__ bv,
    __half* __restrict__ out) {
  __shared__ _Float16 wL[64][128];   // swizzled: 16B chunk c stored at chunk (c ^ (j&7))
  __shared__ _Float16 fL[64][136];   // fused rows, +16B pad to break bank stride
  __shared__ float attL[64][16];
  const int tid = threadIdx.x;
  const int wv = tid >> 6, lane = tid & 63;
  const int q = lane >> 4, m = lane & 15;
  const int r0 = (int)blockIdx.x * 64;

  // stage attw: 64 nodes x 16 floats, 4 floats/thread, coalesced
  {
    int idx = tid * 4;
    int rr = idx >> 4;
    float4 v = make_float4(0.f, 0.f, 0.f, 0.f);
    if (r0 + rr < NN) v = *(const float4*)&attw[(size_t)(r0 + rr) * 16 + (idx & 15)];
    *(float4*)&attL[rr][idx & 15] = v;
  }
  // stage W: 64 x 128 fp32 -> fp16, swizzled
  for (int idx = tid; idx < 64 * 32; idx += 256) {
    int j = idx >> 5;
    int c4 = (idx & 31) * 4;
    float4 v = *(const float4*)&W[(size_t)j * 128 + c4];
    int cs = ((((c4 >> 3) ^ (j & 7)) << 3) | (c4 & 7));
    *(half4v*)&wL[j][cs] = (half4v){(_Float16)v.x, (_Float16)v.y,
                                    (_Float16)v.z, (_Float16)v.w};
  }
  __syncthreads();   // attL (and wL) ready

  // weighted snapshot sum: thread owns 4 chunks of 8 contiguous dims
  // chunk j: flat elem = j*2048 + tid*8 -> row = j*16 + tid/16, dim = (tid&15)*8
  float f[4][8];
#pragma unroll
  for (int j = 0; j < 4; ++j)
#pragma unroll
    for (int e = 0; e < 8; ++e) f[j][e] = 0.f;
  const int trow = tid >> 4;
  const int tdim = (tid & 15) * 8;
  for (int k = 0; k <= KIT; ++k) {
    const __half* src = XS + (size_t)k * NHF + (size_t)r0 * 128;
    half8 v[4];
    float wk[4];
#pragma unroll
    for (int j = 0; j < 4; ++j) {
      int row = j * 16 + trow;
      if (r0 + row < NN) {
        v[j] = *(const half8*)(src + (size_t)row * 128 + tdim);
        wk[j] = attL[row][k];
      } else {
        v[j] = (half8)(_Float16)0.f;
        wk[j] = 0.f;
      }
    }
#pragma unroll
    for (int j = 0; j < 4; ++j)
#pragma unroll
      for (int e = 0; e < 8; ++e) f[j][e] = fmaf(wk[j], (float)v[j][e], f[j][e]);
  }
#pragma unroll
  for (int j = 0; j < 4; ++j) {
    int row = j * 16 + trow;
    half8 hv;
#pragma unroll
    for (int e = 0; e < 8; ++e) hv[e] = (_Float16)f[j][e];
    *(half8*)&fL[row][tdim] = hv;
  }
  __syncthreads();

  // MFMA: wave wv computes rows wv*16 .. wv*16+15 of this 64-row block
  floatx4 acc[4];
#pragma unroll
  for (int jt = 0; jt < 4; ++jt) acc[jt] = (floatx4)(0.f);
#pragma unroll
  for (int s = 0; s < 4; ++s) {
    half8 av = *(const half8*)&fL[wv * 16 + m][s * 32 + q * 8];
    int kq = s * 4 + q;
#pragma unroll
    for (int jt = 0; jt < 4; ++jt) {
      int j = jt * 16 + m;
      half8 b = *(const half8*)&wL[j][(kq ^ (j & 7)) << 3];
      acc[jt] = __builtin_amdgcn_mfma_f32_16x16x32_f16(av, b, acc[jt], 0, 0, 0);
    }
  }
  // epilogue: BN + ReLU -> out[r][j] fp16 (JR = 64)
#pragma unroll
  for (int jt = 0; jt < 4; ++jt) {
    int j = jt * 16 + m;
    float sc = bg[j] * rsqrtf(bv[j] + 1e-5f);
    float sh = (lb[j] - bm[j]) * sc + bb[j];
#pragma unroll
    for (int reg = 0; reg < 4; ++reg) {
      int r = r0 + wv * 16 + q * 4 + reg;
      if (r < NN) {
        float y = fmaxf(fmaf(acc[jt][reg], sc, sh), 0.f);
        out[(size_t)r * 64 + j] = __float2half_rn(y);
      }
    }
  }
}

// recompute-path variant: fused (+)= attw[:,k] * h (h fp16, fused fp32 for accumulation)
__global__ __launch_bounds__(256) void fused_accum_kernel(const __half* __restrict__ h,
                                                          const float* __restrict__ attw,
                                                          float* __restrict__ fused, int k) {
  int node = __builtin_amdgcn_readfirstlane((int)blockIdx.x * 4 + (int)(threadIdx.x >> 6));
  if (node >= NN) return;
  int lane = threadIdx.x & 63;
  float wk = attw[node * 16 + k];
  float2 v = __half22float2(((const __half2*)h)[(size_t)node * 64 + lane]);
  float2 o;
  if (k == 0) {
    o = make_float2(wk * v.x, wk * v.y);
  } else {
    float2 f = ((const float2*)fused)[(size_t)node * 64 + lane];
    o = make_float2(fmaf(wk, v.x, f.x), fmaf(wk, v.y, f.y));
  }
  ((float2*)fused)[(size_t)node * 64 + lane] = o;
}

extern "C" void kernel_launch(void* const* d_in, const int* in_sizes, int n_in,
                              void* d_out, int out_size, void* d_ws, size_t ws_size,
                              hipStream_t stream) {
  (void)in_sizes; (void)n_in; (void)out_size;
  const float* x      = (const float*)d_in[0];
  const int*   ei     = (const int*)d_in[1];
  const float* ew     = (const float*)d_in[2];
  const float* lin1_w = (const float*)d_in[3];
  const float* lin1_b = (const float*)d_in[4];
  const float* bn1_g  = (const float*)d_in[5];
  const float* bn1_b  = (const float*)d_in[6];
  const float* bn1_m  = (const float*)d_in[7];
  const float* bn1_v  = (const float*)d_in[8];
  const float* lin2_w = (const float*)d_in[9];
  const float* lin2_b = (const float*)d_in[10];
  const float* bn2_g  = (const float*)d_in[11];
  const float* bn2_b  = (const float*)d_in[12];
  const float* bn2_m  = (const float*)d_in[13];
  const float* bn2_v  = (const float*)d_in[14];
  const float* att1_w = (const float*)d_in[15];
  const float* att1_b = (const float*)d_in[16];
  const float* att2_w = (const float*)d_in[17];
  const float* att2_b = (const float*)d_in[18];
  const float* head1_w= (const float*)d_in[19];
  const float* head1_b= (const float*)d_in[20];
  const float* bn3_g  = (const float*)d_in[21];
  const float* bn3_b  = (const float*)d_in[22];
  const float* bn3_m  = (const float*)d_in[23];
  const float* bn3_v  = (const float*)d_in[24];
  const float* head2_w= (const float*)d_in[25];
  const float* head2_b= (const float*)d_in[26];
  float* out = (float*)d_out;

  char* p = (char*)d_ws;
  auto alloc = [&](size_t bytes) -> void* {
    void* r = (void*)p;
    p += (bytes + 255) & ~(size_t)255;
    return r;
  };
  // persistent buffers (live across whole launch)
  int*   row_start= (int*)alloc((size_t)(NN + 1) * 4);
  int*   bsum     = (int*)alloc((size_t)256 * 4);
  int*   boff     = (int*)alloc((size_t)256 * 4);
  int*   deg      = (int*)alloc((size_t)NN * 4);
  float* wsum     = (float*)alloc((size_t)NN * 4);
  long*  csr      = (long*)alloc(((size_t)EE + 8 * NN) * 8);  // padded rows (<=7/node)
  float* attw     = (float*)alloc((size_t)NN * 16 * 4);
  __half* h1      = (__half*)alloc((size_t)NHF * 2);
  __half* zbuf    = (__half*)alloc((size_t)NN * 64 * 2);
  size_t common = (size_t)(p - (char*)d_ws);
  size_t stored_need = common + (size_t)(KIT + 1) * NHF * 2 + 4096;
  bool stored = ws_size >= stored_need;

  // preprocessing temporaries overlay XS[8..10] (dead until prop k=7) in stored path.
  __half* XS = nullptr;
  int* pdeg; float* pwsum; int* rank;
  if (stored) {
    XS = (__half*)alloc((size_t)(KIT + 1) * NHF * 2);
    char* ovl = (char*)(XS + (size_t)8 * NHF);
    pdeg  = (int*)ovl;
    pwsum = (float*)(ovl + (size_t)CC * NN * 4);
    rank  = (int*)(ovl + 2 * (size_t)CC * NN * 4);
  } else {
    pdeg  = (int*)alloc((size_t)CC * NN * 4);
    pwsum = (float*)alloc((size_t)CC * NN * 4);
    rank  = (int*)alloc((size_t)EE * 4);
  }

  const int GE  = (EE + 255) / 256;          // edge-parallel grid
  const int GN  = (NN + 255) / 256;          // node-parallel grid (196)
  const int GT  = (NN / 16 + 3) / 4;         // dense v2 grid: 3125 wave-tiles -> 782 blocks
  const int GP  = (NN + 3) / 4;              // wave-per-node grids (12500)
  const int GP2 = (NN / 2 + 3) / 4;          // wave-per-2-nodes prop grid (6250)

  // graph preprocessing (atomic-free)
  hist2_kernel<<<dim3(CC, 2 * RRH), 256, 0, stream>>>(ei, ew, pdeg, pwsum, rank);
  reduce_kernel<<<GN, 256, 0, stream>>>(pdeg, pwsum, deg, wsum, bsum);
  scan2_kernel<<<1, 256, 0, stream>>>(bsum, boff, row_start, GN, NN);
  scan3_kernel<<<GN, 256, 0, stream>>>(deg, boff, row_start, NN);
  csr_fill_kernel<<<GE, 256, 0, stream>>>(ei, ew, wsum, row_start, pdeg, rank,
                                          (int2*)csr, EE);
  pad_fill_kernel<<<GN, 256, 0, stream>>>(deg, row_start, csr);

  if (stored) {
    mfma_dense2<128, 128, 128, 128, 1, false, float, __half><<<GT, 256, 0, stream>>>(
        x, (const float*)nullptr, lin1_w, lin1_b, bn1_g, bn1_b, bn1_m, bn1_v, nullptr, h1);
    mfma_dense2<128, 128, 128, 128, 1, true, __half, __half><<<GT, 256, 0, stream>>>(
        h1, (const __half*)nullptr, lin2_w, lin2_b, bn2_g, bn2_b, bn2_m, bn2_v, h1, XS);
    for (int k = 0; k < KIT; ++k) {
      prop_kernel<<<GP2, 256, 0, stream>>>(XS + (size_t)k * NHF, XS, row_start,
                                           csr, XS + (size_t)(k + 1) * NHF);
    }
    // att1 with fused att2 + softmax (writes attw directly)
    mfma_dense2<256, 128, 64, 64, 2, false, __half, __half, true>
        <<<GT, 256, 0, stream>>>(
        XS, XS + (size_t)KIT * NHF, att1_w, att1_b, nullptr, nullptr, nullptr, nullptr,
        nullptr, (__half*)nullptr, att2_w, att2_b, attw);
    // head1 with LDS-staged coalesced attention-gather
    head1_fg_kernel<<<GT, 256, 0, stream>>>(XS, attw, head1_w, head1_b,
                                            bn3_g, bn3_b, bn3_m, bn3_v, zbuf);
  } else {
    float*  fusedF = (float*)alloc((size_t)NHF * 4);
    __half* base   = (__half*)alloc((size_t)NHF * 2);
    __half* hA     = (__half*)alloc((size_t)NHF * 2);
    __half* hB     = (__half*)alloc((size_t)NHF * 2);
    mfma_dense2<128, 128, 128, 128, 1, false, float, __half><<<GT, 256, 0, stream>>>(
        x, (const float*)nullptr, lin1_w, lin1_b, bn1_g, bn1_b, bn1_m, bn1_v, nullptr, h1);
    mfma_dense2<128, 128, 128, 128, 1, true, __half, __half><<<GT, 256, 0, stream>>>(
        h1, (const __half*)nullptr, lin2_w, lin2_b, bn2_g, bn2_b, bn2_m, bn2_v, h1, base);
    // pass 1: get xs10
    const __half* cur = base;
    for (int k = 1; k <= KIT; ++k) {
      __half* nxt = (k & 1) ? hA : hB;
      prop_kernel<<<GP2, 256, 0, stream>>>(cur, base, row_start, csr, nxt);
      cur = nxt;
    }
    mfma_dense2<256, 128, 64, 64, 2, false, __half, __half, true>
        <<<GT, 256, 0, stream>>>(
        base, cur, att1_w, att1_b, nullptr, nullptr, nullptr, nullptr,
        nullptr, (__half*)nullptr, att2_w, att2_b, attw);
    // pass 2: re-propagate, accumulate fused on the fly (fp32 accumulator)
    fused_accum_kernel<<<GP, 256, 0, stream>>>(base, attw, fusedF, 0);
    cur = base;
    for (int k = 1; k <= KIT; ++k) {
      __half* nxt = (k & 1) ? hA : hB;
      prop_kernel<<<GP2, 256, 0, stream>>>(cur, base, row_start, csr, nxt);
      fused_accum_kernel<<<GP, 256, 0, stream>>>(nxt, attw, fusedF, k);
      cur = nxt;
    }
    mfma_dense2<128, 128, 64, 64, 1, false, float, __half><<<GT, 256, 0, stream>>>(
        fusedF, (const float*)nullptr, head1_w, head1_b, bn3_g, bn3_b, bn3_m, bn3_v,
        nullptr, zbuf);
  }

  // head2 (z fp16 -> out fp32)
  mfma_dense2<64, 64, 48, 40, 0, false, __half, float><<<GT, 256, 0, stream>>>(
      zbuf, (const __half*)nullptr, head2_w, head2_b, nullptr, nullptr, nullptr, nullptr,
      nullptr, out);
}

// Round 8
// 539.704 us; speedup vs baseline: 3.5985x; 1.0053x over previous
//
#include <hip/hip_runtime.h>
#include <hip/hip_fp16.h>
#include <math.h>

#define NN 50000
#define EE 800000
#define HH 128
#define KIT 10
#define NHF (NN * HH)     // 6,400,000 elements per snapshot
#define CC 64             // edge chunks
#define CH 12500          // edges per chunk (divisible by 4; byte offset 16B-aligned)
#define RRH 4             // node ranges per mode
#define NRH 12500         // nodes per range (50KB LDS)

typedef _Float16 half8 __attribute__((ext_vector_type(8)));
typedef _Float16 half4v __attribute__((ext_vector_type(4)));
typedef float floatx4 __attribute__((ext_vector_type(4)));

static_assert(NN % 16 == 0, "row tiles must be exact");

__device__ __forceinline__ float gelu_exact(float x) {
  return 0.5f * x * (1.f + erff(x * 0.70710678118654752f));
}

// typed 4-float load/store helpers (fp32 or fp16 storage)
__device__ __forceinline__ float4 ld4(const float* p) { return *(const float4*)p; }
__device__ __forceinline__ float4 ld4(const __half* p) {
  const __half2* q = (const __half2*)p;
  float2 lo = __half22float2(q[0]);
  float2 hi = __half22float2(q[1]);
  return make_float4(lo.x, lo.y, hi.x, hi.y);
}
__device__ __forceinline__ void st1(float* p, float v) { *p = v; }
__device__ __forceinline__ void st1(__half* p, float v) { *p = __float2half_rn(v); }

// ---------------- graph preprocessing (NO global atomics) ----------------
__global__ __launch_bounds__(256) void hist2_kernel(const int* __restrict__ ei,
                                                    const float* __restrict__ ew,
                                                    int* __restrict__ pdeg,
                                                    float* __restrict__ pwsum,
                                                    int* __restrict__ rank) {
  __shared__ int hist[NRH];
  const int c = blockIdx.x;
  const int z = blockIdx.y;
  const bool isdeg = (z < RRH);
  const int lo = (isdeg ? z : z - RRH) * NRH;
  for (int i = threadIdx.x; i < NRH; i += 256) hist[i] = 0;   // 0 bits == 0.f
  __syncthreads();
  const int e0 = c * CH;
  if (isdeg) {
    const int4* d4 = (const int4*)(ei + (size_t)EE + e0);
    for (int i = threadIdx.x; i < CH / 4; i += 256) {
      int4 d = d4[i];
      int e = e0 + i * 4;
      unsigned u0 = (unsigned)(d.x - lo), u1 = (unsigned)(d.y - lo);
      unsigned u2 = (unsigned)(d.z - lo), u3 = (unsigned)(d.w - lo);
      if (u0 < NRH) rank[e]     = atomicAdd(&hist[u0], 1);
      if (u1 < NRH) rank[e + 1] = atomicAdd(&hist[u1], 1);
      if (u2 < NRH) rank[e + 2] = atomicAdd(&hist[u2], 1);
      if (u3 < NRH) rank[e + 3] = atomicAdd(&hist[u3], 1);
    }
    __syncthreads();
    for (int i = threadIdx.x; i < NRH; i += 256)
      pdeg[(size_t)c * NN + lo + i] = hist[i];
  } else {
    float* whist = (float*)hist;
    const int4* s4 = (const int4*)(ei + e0);
    const float4* w4 = (const float4*)(ew + e0);
    for (int i = threadIdx.x; i < CH / 4; i += 256) {
      int4 s = s4[i];
      float4 w = w4[i];
      unsigned u0 = (unsigned)(s.x - lo), u1 = (unsigned)(s.y - lo);
      unsigned u2 = (unsigned)(s.z - lo), u3 = (unsigned)(s.w - lo);
      if (u0 < NRH) atomicAdd(&whist[u0], w.x);
      if (u1 < NRH) atomicAdd(&whist[u1], w.y);
      if (u2 < NRH) atomicAdd(&whist[u2], w.z);
      if (u3 < NRH) atomicAdd(&whist[u3], w.w);
    }
    __syncthreads();
    for (int i = threadIdx.x; i < NRH; i += 256)
      pwsum[(size_t)c * NN + lo + i] = whist[i];
  }
}

// per-node: deg = sum over chunks (pdeg -> in-place exclusive chunk prefix),
// wsum = sum over chunks; block-reduce PADDED deg -> bsum (rows padded to mult of 8).
__global__ __launch_bounds__(256) void reduce_kernel(int* __restrict__ pdeg,
                                                     const float* __restrict__ pwsum,
                                                     int* __restrict__ deg,
                                                     float* __restrict__ wsum,
                                                     int* __restrict__ bsum) {
  int node = blockIdx.x * 256 + threadIdx.x;
  int acc = 0; float wacc = 0.f;
  if (node < NN) {
    for (int c = 0; c < CC; ++c) {
      size_t idx = (size_t)c * NN + node;
      int t = pdeg[idx];
      pdeg[idx] = acc;        // exclusive prefix over chunks
      acc += t;
      wacc += pwsum[idx];
    }
    deg[node] = acc;          // real degree
    wsum[node] = wacc;
  }
  __shared__ int red[256];
  red[threadIdx.x] = (node < NN) ? ((acc + 7) & ~7) : 0;   // padded degree
  __syncthreads();
  for (int off = 128; off > 0; off >>= 1) {
    if (threadIdx.x < off) red[threadIdx.x] += red[threadIdx.x + off];
    __syncthreads();
  }
  if (threadIdx.x == 0) bsum[blockIdx.x] = red[0];
}

__global__ __launch_bounds__(256) void scan2_kernel(const int* __restrict__ bsum,
                                                    int* __restrict__ boff,
                                                    int* __restrict__ row_start, int nb, int n) {
  __shared__ int buf[256];
  int tid = threadIdx.x;
  int v = (tid < nb) ? bsum[tid] : 0;
  buf[tid] = v;
  __syncthreads();
  for (int off = 1; off < 256; off <<= 1) {
    int t = (tid >= off) ? buf[tid - off] : 0;
    __syncthreads();
    buf[tid] += t;
    __syncthreads();
  }
  if (tid < nb) boff[tid] = buf[tid] - v;  // exclusive prefix
  if (tid == 255) row_start[n] = buf[255];
}

// scan over PADDED degrees -> row_start
__global__ __launch_bounds__(256) void scan3_kernel(const int* __restrict__ deg,
                                                    const int* __restrict__ boff,
                                                    int* __restrict__ row_start, int n) {
  __shared__ int buf[256];
  int tid = threadIdx.x;
  int i = blockIdx.x * 256 + tid;
  int v = (i < n) ? ((deg[i] + 7) & ~7) : 0;
  buf[tid] = v;
  __syncthreads();
  for (int off = 1; off < 256; off <<= 1) {
    int t = (tid >= off) ? buf[tid - off] : 0;
    __syncthreads();
    buf[tid] += t;
    __syncthreads();
  }
  if (i < n) row_start[i] = boff[blockIdx.x] + buf[tid] - v;
}

__global__ __launch_bounds__(256) void csr_fill_kernel(const int* __restrict__ ei,
                                                       const float* __restrict__ ew,
                                                       const float* __restrict__ wsum,
                                                       const int* __restrict__ row_start,
                                                       const int* __restrict__ pdeg_excl,
                                                       const int* __restrict__ rank,
                                                       int2* __restrict__ csr, int e_cnt) {
  int e = blockIdx.x * 256 + threadIdx.x;
  if (e >= e_cnt) return;
  int c = e / CH;
  int src = ei[e], dst = ei[EE + e];
  float ws = wsum[src];
  ws = ws < 1.f ? 1.f : ws;
  float v = 0.9f * ew[e] / ws;            // (1-ALPHA) * enorm folded together
  int pos = row_start[dst] + pdeg_excl[(size_t)c * NN + dst] + rank[e];
  csr[pos] = make_int2(src, __float_as_int(v));
}

// fill pad slots [row_start+deg, row_start_next) with (src=0, w=+0.f): contributes 0.
__global__ __launch_bounds__(256) void pad_fill_kernel(const int* __restrict__ deg,
                                                       const int* __restrict__ row_start,
                                                       long* __restrict__ csr) {
  int node = blockIdx.x * 256 + threadIdx.x;
  if (node >= NN) return;
  int s = row_start[node] + deg[node];
  int e = row_start[node + 1];
  for (int i = s; i < e; ++i) csr[i] = 0;
}

// ---------------- propagation: one wave per 2 consecutive nodes, fp16 h ----------------
// CSR rows padded to multiples of 8 -> tail-free. Two consecutive nodes have CONTIGUOUS
// CSR segments; one pipelined 8-edge batch stream covers both; wave-uniform flag selects
// the accumulator. (R2-proven version — per-dispatch loop; fused/coop variants measured
// WORSE: R3 plane-split 2x slower, R5 fence-barrier 5x slower from L2-invalidate storms.)
__device__ __forceinline__ void prop_pair(int nA, int lane,
                                          const __half2* __restrict__ hc,
                                          const __half2* __restrict__ bp,
                                          const int* __restrict__ row_start,
                                          const long* __restrict__ csr,
                                          __half2* __restrict__ np) {
  int nB = nA + 1;
  float2 vbA = __half22float2(bp[(size_t)nA * 64 + lane]);
  float2 vbB = __half22float2(bp[(size_t)nB * 64 + lane]);
  float aAx = 0.1f * vbA.x, aAy = 0.1f * vbA.y, bAx = 0.f, bAy = 0.f;
  float aBx = 0.1f * vbB.x, aBy = 0.1f * vbB.y, bBx = 0.f, bBy = 0.f;
  int s  = __builtin_amdgcn_readfirstlane(row_start[nA]);
  int eA = __builtin_amdgcn_readfirstlane(row_start[nA + 1]);
  int eB = __builtin_amdgcn_readfirstlane(row_start[nB + 1]);
  int nb = (eB - s) >> 3;          // all batches full (padded)
  int i = s;
  if (nb > 0) {
    long cur[8];
    bool curB = (i >= eA);
#pragma unroll
    for (int j = 0; j < 8; ++j) cur[j] = csr[i + j];
    i += 8;
    for (int bidx = 1; bidx < nb; ++bidx) {
      long nxt[8];
      bool nxtB = (i >= eA);
#pragma unroll
      for (int j = 0; j < 8; ++j) nxt[j] = csr[i + j];
      i += 8;
      float2 g[8];
#pragma unroll
      for (int j = 0; j < 8; ++j) g[j] = __half22float2(hc[(size_t)(int)cur[j] * 64 + lane]);
      if (curB) {
#pragma unroll
        for (int j = 0; j < 8; ++j) {
          float v = __int_as_float((int)(cur[j] >> 32));
          if (j & 1) { bBx = fmaf(v, g[j].x, bBx); bBy = fmaf(v, g[j].y, bBy); }
          else       { aBx = fmaf(v, g[j].x, aBx); aBy = fmaf(v, g[j].y, aBy); }
        }
      } else {
#pragma unroll
        for (int j = 0; j < 8; ++j) {
          float v = __int_as_float((int)(cur[j] >> 32));
          if (j & 1) { bAx = fmaf(v, g[j].x, bAx); bAy = fmaf(v, g[j].y, bAy); }
          else       { aAx = fmaf(v, g[j].x, aAx); aAy = fmaf(v, g[j].y, aAy); }
        }
      }
#pragma unroll
      for (int j = 0; j < 8; ++j) cur[j] = nxt[j];
      curB = nxtB;
    }
    float2 g[8];
#pragma unroll
    for (int j = 0; j < 8; ++j) g[j] = __half22float2(hc[(size_t)(int)cur[j] * 64 + lane]);
    if (curB) {
#pragma unroll
      for (int j = 0; j < 8; ++j) {
        float v = __int_as_float((int)(cur[j] >> 32));
        if (j & 1) { bBx = fmaf(v, g[j].x, bBx); bBy = fmaf(v, g[j].y, bBy); }
        else       { aBx = fmaf(v, g[j].x, aBx); aBy = fmaf(v, g[j].y, aBy); }
      }
    } else {
#pragma unroll
      for (int j = 0; j < 8; ++j) {
        float v = __int_as_float((int)(cur[j] >> 32));
        if (j & 1) { bAx = fmaf(v, g[j].x, bAx); bAy = fmaf(v, g[j].y, bAy); }
        else       { aAx = fmaf(v, g[j].x, aAx); aAy = fmaf(v, g[j].y, aAy); }
      }
    }
  }
  np[(size_t)nA * 64 + lane] = __float22half2_rn(make_float2(aAx + bAx, aAy + bAy));
  np[(size_t)nB * 64 + lane] = __float22half2_rn(make_float2(aBx + bBx, aBy + bBy));
}

__global__ __launch_bounds__(256, 6) void prop_kernel(const __half* __restrict__ h_cur,
                                                      const __half* __restrict__ base,
                                                      const int* __restrict__ row_start,
                                                      const long* __restrict__ csr,
                                                      __half* __restrict__ h_next) {
  int pair = __builtin_amdgcn_readfirstlane((int)blockIdx.x * 4 + (int)(threadIdx.x >> 6));
  if (pair * 2 >= NN) return;
  prop_pair(pair * 2, threadIdx.x & 63, (const __half2*)h_cur, (const __half2*)base,
            row_start, csr, (__half2*)h_next);
}

// ---------------- MFMA dense v2: out[n][j] = act(sum_k X[n][k] * W[j][k] + ...) ----------
// One 16-row tile per wave. X rows wave-private -> A-fragments direct from global; only W
// staged in LDS (fp16, XOR-swizzled).
// ATT2 variant (att1 only, JP=64): epilogue stages the fp16-rounded gelu outputs in LDS
//   (reusing wL after a barrier), then 64 threads compute att2 (11x64) + softmax and
//   write attw directly — bit-identical inputs to the old att2_softmax kernel.
template <int K, int KA, int JP, int JR, int ACT, bool RESID, typename IT, typename OT,
          bool ATT2 = false>
__global__ __launch_bounds__(256) void mfma_dense2(
    const IT* __restrict__ Xa, const IT* __restrict__ Xb,
    const float* __restrict__ W, const float* __restrict__ lb,
    const float* __restrict__ bg, const float* __restrict__ bb,
    const float* __restrict__ bm, const float* __restrict__ bv,
    const OT* __restrict__ resid, OT* __restrict__ out,
    const float* __restrict__ W2 = nullptr,
    const float* __restrict__ b2 = nullptr,
    float* __restrict__ attw_out = nullptr) {
  static_assert(K % 32 == 0 && KA % 32 == 0 && JP % 16 == 0, "");
  constexpr int JT = JP / 16;      // 16-col MFMA tiles
  constexpr int NS = K / 32;       // K-slices of 32
  constexpr bool ISF = __is_same(IT, float);
  __shared__ _Float16 wL[JP][K];   // swizzled: 16B chunk c stored at chunk (c ^ (j&7))
  static_assert(!ATT2 || (JP == 64 && JR == 64 && sizeof(wL) >= 64 * 65 * 4), "");

  const int tid = threadIdx.x;
  const int wv = tid >> 6, lane = tid & 63;
  const int q = lane >> 4, m = lane & 15;
  const int t = blockIdx.x * 4 + wv;           // tile id (16 rows)
  const bool active = (t < NN / 16);
  const int row = t * 16 + m;

  // ---- issue per-lane A-fragment loads (direct global, 16B each) ----
  half8  a[ISF ? 1 : NS];
  float4 af0[ISF ? NS : 1], af1[ISF ? NS : 1];
  if (active) {
#pragma unroll
    for (int s = 0; s < NS; ++s) {
      int c = s * 32 + q * 8;
      if constexpr (ISF) {
        const float* p = (const float*)Xa + (size_t)row * K + c;
        af0[s] = *(const float4*)p;
        af1[s] = *(const float4*)(p + 4);
      } else {
        const __half* p = (c < KA) ? (const __half*)Xa + (size_t)row * KA + c
                                   : (const __half*)Xb + (size_t)row * (K - KA) + (c - KA);
        a[s] = *(const half8*)p;
      }
    }
  }

  // ---- stage W: fp32 -> fp16, swizzled LDS; zero-fill rows j >= JR ----
  constexpr int C4 = K / 4;
  for (int idx = tid; idx < JP * C4; idx += 256) {
    int j = idx / C4;
    int c4 = (idx % C4) * 4;
    float4 v = make_float4(0.f, 0.f, 0.f, 0.f);
    if (j < JR) v = *(const float4*)&W[(size_t)j * K + c4];
    int cs = ((((c4 >> 3) ^ (j & 7)) << 3) | (c4 & 7));
    *(half4v*)&wL[j][cs] = (half4v){(_Float16)v.x, (_Float16)v.y,
                                    (_Float16)v.z, (_Float16)v.w};
  }
  __syncthreads();

  if constexpr (!ATT2) {
    if (!active) return;
  }

  floatx4 acc[JT];
#pragma unroll
  for (int jt = 0; jt < JT; ++jt) acc[jt] = (floatx4)(0.f);

  if (active) {
#pragma unroll
    for (int s = 0; s < NS; ++s) {
      half8 av;
      if constexpr (ISF) {
        float4 f0 = af0[s], f1 = af1[s];
        av = (half8){(_Float16)f0.x, (_Float16)f0.y, (_Float16)f0.z, (_Float16)f0.w,
                     (_Float16)f1.x, (_Float16)f1.y, (_Float16)f1.z, (_Float16)f1.w};
      } else {
        av = a[s];
      }
      int kq = s * 4 + q;                        // 16B chunk index within row
#pragma unroll
      for (int jt = 0; jt < JT; ++jt) {
        int j = jt * 16 + m;
        half8 b = *(const half8*)&wL[j][(kq ^ (j & 7)) << 3];
        acc[jt] = __builtin_amdgcn_mfma_f32_16x16x32_f16(av, b, acc[jt], 0, 0, 0);
      }
    }
  }

  if constexpr (ATT2) {
    // ---- fused att2 + softmax (att1 instantiation only) ----
    float* attL = (float*)&wL[0][0];   // reuse wL (32KB >= 64*65*4B) after barrier
    __syncthreads();                   // all waves done reading wL
    if (active) {
#pragma unroll
      for (int jt = 0; jt < JT; ++jt) {
        int j = jt * 16 + m;
        float sh = lb[j];
#pragma unroll
        for (int reg = 0; reg < 4; ++reg) {
          float y = gelu_exact(acc[jt][reg] + sh);
          // fp16 round-trip: bit-identical to old gbuf(fp16) -> att2 path
          y = __half2float(__float2half_rn(y));
          attL[(wv * 16 + q * 4 + reg) * 65 + j] = y;
        }
      }
    }
    __syncthreads();
    if (tid < 64) {
      int n = blockIdx.x * 64 + tid;
      if (n < NN) {
        float a2[KIT + 1];
#pragma unroll
        for (int j = 0; j < KIT + 1; ++j) {
          float acc2 = b2[j];
#pragma unroll
          for (int k = 0; k < 64; ++k) acc2 = fmaf(attL[tid * 65 + k], W2[j * 64 + k], acc2);
          a2[j] = acc2;
        }
        float mx = a2[0];
#pragma unroll
        for (int j = 1; j < KIT + 1; ++j) mx = fmaxf(mx, a2[j]);
        float ssum = 0.f;
#pragma unroll
        for (int j = 0; j < KIT + 1; ++j) { a2[j] = expf(a2[j] - mx); ssum += a2[j]; }
        float inv = 1.f / ssum;
#pragma unroll
        for (int j = 0; j < KIT + 1; ++j) attw_out[n * 16 + j] = a2[j] * inv;
      }
    }
    return;
  }

  // epilogue: lane holds col j = jt*16 + m, rows q*4 + reg
#pragma unroll
  for (int jt = 0; jt < JT; ++jt) {
    int j = jt * 16 + m;
    if (j >= JR) continue;
    float sc = 0.f, sh;
    if (ACT == 1) {
      sc = bg[j] * rsqrtf(bv[j] + 1e-5f);
      sh = (lb[j] - bm[j]) * sc + bb[j];
    } else {
      sh = lb[j];
    }
#pragma unroll
    for (int reg = 0; reg < 4; ++reg) {
      int r = t * 16 + q * 4 + reg;
      float aa = acc[jt][reg];
      float y;
      if (ACT == 0)      y = aa + sh;
      else if (ACT == 1) y = fmaxf(fmaf(aa, sc, sh), 0.f);
      else               y = gelu_exact(aa + sh);
      if (RESID) y += (float)resid[(size_t)r * JR + j];
      st1(&out[(size_t)r * JR + j], y);
    }
  }
}

// ---------------- lin1 + lin2 fused (stored path) ----------------
// Per 64-row block: MFMA1 (x fp32 -> h1 tile) with W1 in LDS; h1 (fp16-rounded,
// identical values to the old global h1 buffer) stays in LDS; W2 restages into the
// same LDS region after a barrier; MFMA2 + BN2/ReLU + residual(h1) writes XS0.
// Bitwise-identical arithmetic to the old lin1->lin2 dispatch pair.
__global__ __launch_bounds__(256) void lin12_kernel(
    const float* __restrict__ x,
    const float* __restrict__ W1, const float* __restrict__ b1,
    const float* __restrict__ g1, const float* __restrict__ be1,
    const float* __restrict__ m1, const float* __restrict__ v1,
    const float* __restrict__ W2, const float* __restrict__ b2,
    const float* __restrict__ g2, const float* __restrict__ be2,
    const float* __restrict__ m2, const float* __restrict__ v2,
    __half* __restrict__ out) {
  __shared__ _Float16 wL[128][128];   // swizzled W (stage 1: W1, stage 2: W2)
  __shared__ _Float16 hL[64][136];    // h1 tile, +8 halves pad (2-way bank alias only)
  const int tid = threadIdx.x;
  const int wv = tid >> 6, lane = tid & 63;
  const int q = lane >> 4, m = lane & 15;
  const int r0 = (int)blockIdx.x * 64;
  const int row = r0 + wv * 16 + m;
  const bool active = (row < NN);

  // A-fragments from x (fp32, direct global) — issued before W1 staging
  float4 af0[4], af1[4];
  if (active) {
#pragma unroll
    for (int s = 0; s < 4; ++s) {
      const float* p = x + (size_t)row * 128 + s * 32 + q * 8;
      af0[s] = *(const float4*)p;
      af1[s] = *(const float4*)(p + 4);
    }
  }
  // stage W1 (128x128 fp32 -> fp16, swizzled)
  for (int idx = tid; idx < 128 * 32; idx += 256) {
    int j = idx >> 5;
    int c4 = (idx & 31) * 4;
    float4 v = *(const float4*)&W1[(size_t)j * 128 + c4];
    int cs = ((((c4 >> 3) ^ (j & 7)) << 3) | (c4 & 7));
    *(half4v*)&wL[j][cs] = (half4v){(_Float16)v.x, (_Float16)v.y,
                                    (_Float16)v.z, (_Float16)v.w};
  }
  __syncthreads();

  // MFMA1
  floatx4 acc1[8];
#pragma unroll
  for (int jt = 0; jt < 8; ++jt) acc1[jt] = (floatx4)(0.f);
#pragma unroll
  for (int s = 0; s < 4; ++s) {
    float4 f0 = af0[s], f1 = af1[s];
    half8 av = (half8){(_Float16)f0.x, (_Float16)f0.y, (_Float16)f0.z, (_Float16)f0.w,
                       (_Float16)f1.x, (_Float16)f1.y, (_Float16)f1.z, (_Float16)f1.w};
    int kq = s * 4 + q;
#pragma unroll
    for (int jt = 0; jt < 8; ++jt) {
      int j = jt * 16 + m;
      half8 b = *(const half8*)&wL[j][(kq ^ (j & 7)) << 3];
      acc1[jt] = __builtin_amdgcn_mfma_f32_16x16x32_f16(av, b, acc1[jt], 0, 0, 0);
    }
  }
  __syncthreads();   // all waves done reading wL (W1)

  // epilogue1: BN1+ReLU -> fp16 h1 tile in LDS; stage W2 into wL concurrently
#pragma unroll
  for (int jt = 0; jt < 8; ++jt) {
    int j = jt * 16 + m;
    float sc = g1[j] * rsqrtf(v1[j] + 1e-5f);
    float sh = (b1[j] - m1[j]) * sc + be1[j];
#pragma unroll
    for (int reg = 0; reg < 4; ++reg) {
      float y = fmaxf(fmaf(acc1[jt][reg], sc, sh), 0.f);
      hL[wv * 16 + q * 4 + reg][j] = (_Float16)y;   // RN cast == __float2half_rn
    }
  }
  for (int idx = tid; idx < 128 * 32; idx += 256) {
    int j = idx >> 5;
    int c4 = (idx & 31) * 4;
    float4 v = *(const float4*)&W2[(size_t)j * 128 + c4];
    int cs = ((((c4 >> 3) ^ (j & 7)) << 3) | (c4 & 7));
    *(half4v*)&wL[j][cs] = (half4v){(_Float16)v.x, (_Float16)v.y,
                                    (_Float16)v.z, (_Float16)v.w};
  }
  __syncthreads();

  // MFMA2 (A from h1 tile)
  floatx4 acc2[8];
#pragma unroll
  for (int jt = 0; jt < 8; ++jt) acc2[jt] = (floatx4)(0.f);
#pragma unroll
  for (int s = 0; s < 4; ++s) {
    half8 av = *(const half8*)&hL[wv * 16 + m][s * 32 + q * 8];
    int kq = s * 4 + q;
#pragma unroll
    for (int jt = 0; jt < 8; ++jt) {
      int j = jt * 16 + m;
      half8 b = *(const half8*)&wL[j][(kq ^ (j & 7)) << 3];
      acc2[jt] = __builtin_amdgcn_mfma_f32_16x16x32_f16(av, b, acc2[jt], 0, 0, 0);
    }
  }
  if (!active) return;
  // epilogue2: BN2+ReLU + residual(h1) -> XS0
#pragma unroll
  for (int jt = 0; jt < 8; ++jt) {
    int j = jt * 16 + m;
    float sc = g2[j] * rsqrtf(v2[j] + 1e-5f);
    float sh = (b2[j] - m2[j]) * sc + be2[j];
#pragma unroll
    for (int reg = 0; reg < 4; ++reg) {
      int r = r0 + wv * 16 + q * 4 + reg;
      float y = fmaxf(fmaf(acc2[jt][reg], sc, sh), 0.f);
      y += (float)hL[wv * 16 + q * 4 + reg][j];
      out[(size_t)r * 128 + j] = __float2half_rn(y);
    }
  }
}

// ---------------- head1 + head2 fused with attention-gather (stored path) ----------------
// Per 64-row block: stage attw + head1_w in LDS; coalesced weighted snapshot sum (fp32
// fmaf, k ascending, fp16 round — R7-verified arithmetic) -> fL; MFMA1 + BN3/ReLU -> z
// (fp16-rounded, identical to old zbuf) back into fL; head2_w restages into wL; MFMA2 +
// bias writes the final output directly. Bit-identical to head1_fg -> head2 pair.
__global__ __launch_bounds__(256) void head12_kernel(
    const __half* __restrict__ XS, const float* __restrict__ attw,
    const float* __restrict__ W, const float* __restrict__ lb,
    const float* __restrict__ bg, const float* __restrict__ bb,
    const float* __restrict__ bm, const float* __restrict__ bv,
    const float* __restrict__ W2, const float* __restrict__ lb2,
    float* __restrict__ out) {
  __shared__ _Float16 wL[64][128];   // stage 1: head1_w swizzled; stage 2: head2_w (48x64)
  __shared__ _Float16 fL[64][136];   // fused rows (stage 1 A); z tile (stage 2 A)
  __shared__ float attL[64][16];
  const int tid = threadIdx.x;
  const int wv = tid >> 6, lane = tid & 63;
  const int q = lane >> 4, m = lane & 15;
  const int r0 = (int)blockIdx.x * 64;

  // stage attw: 64 nodes x 16 floats, 4 floats/thread, coalesced
  {
    int idx = tid * 4;
    int rr = idx >> 4;
    float4 v = make_float4(0.f, 0.f, 0.f, 0.f);
    if (r0 + rr < NN) v = *(const float4*)&attw[(size_t)(r0 + rr) * 16 + (idx & 15)];
    *(float4*)&attL[rr][idx & 15] = v;
  }
  // stage head1_w: 64 x 128 fp32 -> fp16, swizzled
  for (int idx = tid; idx < 64 * 32; idx += 256) {
    int j = idx >> 5;
    int c4 = (idx & 31) * 4;
    float4 v = *(const float4*)&W[(size_t)j * 128 + c4];
    int cs = ((((c4 >> 3) ^ (j & 7)) << 3) | (c4 & 7));
    *(half4v*)&wL[j][cs] = (half4v){(_Float16)v.x, (_Float16)v.y,
                                    (_Float16)v.z, (_Float16)v.w};
  }
  __syncthreads();   // attL (and wL) ready

  // weighted snapshot sum: thread owns 4 chunks of 8 contiguous dims (coalesced)
  float f[4][8];
#pragma unroll
  for (int j = 0; j < 4; ++j)
#pragma unroll
    for (int e = 0; e < 8; ++e) f[j][e] = 0.f;
  const int trow = tid >> 4;
  const int tdim = (tid & 15) * 8;
  for (int k = 0; k <= KIT; ++k) {
    const __half* src = XS + (size_t)k * NHF + (size_t)r0 * 128;
    half8 v[4];
    float wk[4];
#pragma unroll
    for (int j = 0; j < 4; ++j) {
      int row = j * 16 + trow;
      if (r0 + row < NN) {
        v[j] = *(const half8*)(src + (size_t)row * 128 + tdim);
        wk[j] = attL[row][k];
      } else {
        v[j] = (half8)(_Float16)0.f;
        wk[j] = 0.f;
      }
    }
#pragma unroll
    for (int j = 0; j < 4; ++j)
#pragma unroll
      for (int e = 0; e < 8; ++e) f[j][e] = fmaf(wk[j], (float)v[j][e], f[j][e]);
  }
#pragma unroll
  for (int j = 0; j < 4; ++j) {
    int row = j * 16 + trow;
    half8 hv;
#pragma unroll
    for (int e = 0; e < 8; ++e) hv[e] = (_Float16)f[j][e];
    *(half8*)&fL[row][tdim] = hv;
  }
  __syncthreads();

  // MFMA1: wave wv computes rows wv*16 .. +15 (head1: 128 -> 64)
  floatx4 acc[4];
#pragma unroll
  for (int jt = 0; jt < 4; ++jt) acc[jt] = (floatx4)(0.f);
#pragma unroll
  for (int s = 0; s < 4; ++s) {
    half8 av = *(const half8*)&fL[wv * 16 + m][s * 32 + q * 8];
    int kq = s * 4 + q;
#pragma unroll
    for (int jt = 0; jt < 4; ++jt) {
      int j = jt * 16 + m;
      half8 b = *(const half8*)&wL[j][(kq ^ (j & 7)) << 3];
      acc[jt] = __builtin_amdgcn_mfma_f32_16x16x32_f16(av, b, acc[jt], 0, 0, 0);
    }
  }
  __syncthreads();   // all waves done reading fL + wL

  // epilogue1: BN3+ReLU -> z (fp16) into fL cols 0..63; stage head2_w into wL
#pragma unroll
  for (int jt = 0; jt < 4; ++jt) {
    int j = jt * 16 + m;
    float sc = bg[j] * rsqrtf(bv[j] + 1e-5f);
    float sh = (lb[j] - bm[j]) * sc + bb[j];
#pragma unroll
    for (int reg = 0; reg < 4; ++reg) {
      float y = fmaxf(fmaf(acc[jt][reg], sc, sh), 0.f);
      fL[wv * 16 + q * 4 + reg][j] = (_Float16)y;   // RN cast == __float2half_rn
    }
  }
  // head2_w: 48 rows (zero-pad >= 40) x 64 cols, swizzled for K=64
  for (int idx = tid; idx < 48 * 16; idx += 256) {
    int j = idx >> 4;
    int c4 = (idx & 15) * 4;
    float4 v = make_float4(0.f, 0.f, 0.f, 0.f);
    if (j < 40) v = *(const float4*)&W2[(size_t)j * 64 + c4];
    int cs = ((((c4 >> 3) ^ (j & 7)) << 3) | (c4 & 7));
    *(half4v*)&wL[j][cs] = (half4v){(_Float16)v.x, (_Float16)v.y,
                                    (_Float16)v.z, (_Float16)v.w};
  }
  __syncthreads();

  // MFMA2: z (64 dims) x head2_w -> 40 outputs
  floatx4 acc2[3];
#pragma unroll
  for (int jt = 0; jt < 3; ++jt) acc2[jt] = (floatx4)(0.f);
#pragma unroll
  for (int s = 0; s < 2; ++s) {
    half8 av = *(const half8*)&fL[wv * 16 + m][s * 32 + q * 8];
    int kq = s * 4 + q;
#pragma unroll
    for (int jt = 0; jt < 3; ++jt) {
      int j = jt * 16 + m;
      half8 b = *(const half8*)&wL[j][(kq ^ (j & 7)) << 3];
      acc2[jt] = __builtin_amdgcn_mfma_f32_16x16x32_f16(av, b, acc2[jt], 0, 0, 0);
    }
  }
  // epilogue2: + bias -> out fp32 (40 cols)
#pragma unroll
  for (int jt = 0; jt < 3; ++jt) {
    int j = jt * 16 + m;
    if (j >= 40) continue;
    float sh = lb2[j];
#pragma unroll
    for (int reg = 0; reg < 4; ++reg) {
      int r = r0 + wv * 16 + q * 4 + reg;
      if (r < NN) out[(size_t)r * 40 + j] = acc2[jt][reg] + sh;
    }
  }
}

// recompute-path variant: fused (+)= attw[:,k] * h (h fp16, fused fp32 for accumulation)
__global__ __launch_bounds__(256) void fused_accum_kernel(const __half* __restrict__ h,
                                                          const float* __restrict__ attw,
                                                          float* __restrict__ fused, int k) {
  int node = __builtin_amdgcn_readfirstlane((int)blockIdx.x * 4 + (int)(threadIdx.x >> 6));
  if (node >= NN) return;
  int lane = threadIdx.x & 63;
  float wk = attw[node * 16 + k];
  float2 v = __half22float2(((const __half2*)h)[(size_t)node * 64 + lane]);
  float2 o;
  if (k == 0) {
    o = make_float2(wk * v.x, wk * v.y);
  } else {
    float2 f = ((const float2*)fused)[(size_t)node * 64 + lane];
    o = make_float2(fmaf(wk, v.x, f.x), fmaf(wk, v.y, f.y));
  }
  ((float2*)fused)[(size_t)node * 64 + lane] = o;
}

extern "C" void kernel_launch(void* const* d_in, const int* in_sizes, int n_in,
                              void* d_out, int out_size, void* d_ws, size_t ws_size,
                              hipStream_t stream) {
  (void)in_sizes; (void)n_in; (void)out_size;
  const float* x      = (const float*)d_in[0];
  const int*   ei     = (const int*)d_in[1];
  const float* ew     = (const float*)d_in[2];
  const float* lin1_w = (const float*)d_in[3];
  const float* lin1_b = (const float*)d_in[4];
  const float* bn1_g  = (const float*)d_in[5];
  const float* bn1_b  = (const float*)d_in[6];
  const float* bn1_m  = (const float*)d_in[7];
  const float* bn1_v  = (const float*)d_in[8];
  const float* lin2_w = (const float*)d_in[9];
  const float* lin2_b = (const float*)d_in[10];
  const float* bn2_g  = (const float*)d_in[11];
  const float* bn2_b  = (const float*)d_in[12];
  const float* bn2_m  = (const float*)d_in[13];
  const float* bn2_v  = (const float*)d_in[14];
  const float* att1_w = (const float*)d_in[15];
  const float* att1_b = (const float*)d_in[16];
  const float* att2_w = (const float*)d_in[17];
  const float* att2_b = (const float*)d_in[18];
  const float* head1_w= (const float*)d_in[19];
  const float* head1_b= (const float*)d_in[20];
  const float* bn3_g  = (const float*)d_in[21];
  const float* bn3_b  = (const float*)d_in[22];
  const float* bn3_m  = (const float*)d_in[23];
  const float* bn3_v  = (const float*)d_in[24];
  const float* head2_w= (const float*)d_in[25];
  const float* head2_b= (const float*)d_in[26];
  float* out = (float*)d_out;

  char* p = (char*)d_ws;
  auto alloc = [&](size_t bytes) -> void* {
    void* r = (void*)p;
    p += (bytes + 255) & ~(size_t)255;
    return r;
  };
  // persistent buffers (live across whole launch)
  int*   row_start= (int*)alloc((size_t)(NN + 1) * 4);
  int*   bsum     = (int*)alloc((size_t)256 * 4);
  int*   boff     = (int*)alloc((size_t)256 * 4);
  int*   deg      = (int*)alloc((size_t)NN * 4);
  float* wsum     = (float*)alloc((size_t)NN * 4);
  long*  csr      = (long*)alloc(((size_t)EE + 8 * NN) * 8);  // padded rows (<=7/node)
  float* attw     = (float*)alloc((size_t)NN * 16 * 4);
  __half* h1      = (__half*)alloc((size_t)NHF * 2);
  __half* zbuf    = (__half*)alloc((size_t)NN * 64 * 2);
  size_t common = (size_t)(p - (char*)d_ws);
  size_t stored_need = common + (size_t)(KIT + 1) * NHF * 2 + 4096;
  bool stored = ws_size >= stored_need;

  // preprocessing temporaries overlay XS[8..10] (dead until prop k=7) in stored path.
  __half* XS = nullptr;
  int* pdeg; float* pwsum; int* rank;
  if (stored) {
    XS = (__half*)alloc((size_t)(KIT + 1) * NHF * 2);
    char* ovl = (char*)(XS + (size_t)8 * NHF);
    pdeg  = (int*)ovl;
    pwsum = (float*)(ovl + (size_t)CC * NN * 4);
    rank  = (int*)(ovl + 2 * (size_t)CC * NN * 4);
  } else {
    pdeg  = (int*)alloc((size_t)CC * NN * 4);
    pwsum = (float*)alloc((size_t)CC * NN * 4);
    rank  = (int*)alloc((size_t)EE * 4);
  }

  const int GE  = (EE + 255) / 256;          // edge-parallel grid
  const int GN  = (NN + 255) / 256;          // node-parallel grid (196)
  const int GT  = (NN / 16 + 3) / 4;         // dense grid: 3125 wave-tiles -> 782 blocks
  const int GP  = (NN + 3) / 4;              // wave-per-node grids (12500)
  const int GP2 = (NN / 2 + 3) / 4;          // wave-per-2-nodes prop grid (6250)

  // graph preprocessing (atomic-free)
  hist2_kernel<<<dim3(CC, 2 * RRH), 256, 0, stream>>>(ei, ew, pdeg, pwsum, rank);
  reduce_kernel<<<GN, 256, 0, stream>>>(pdeg, pwsum, deg, wsum, bsum);
  scan2_kernel<<<1, 256, 0, stream>>>(bsum, boff, row_start, GN, NN);
  scan3_kernel<<<GN, 256, 0, stream>>>(deg, boff, row_start, NN);
  csr_fill_kernel<<<GE, 256, 0, stream>>>(ei, ew, wsum, row_start, pdeg, rank,
                                          (int2*)csr, EE);
  pad_fill_kernel<<<GN, 256, 0, stream>>>(deg, row_start, csr);

  if (stored) {
    // fused lin1+lin2 -> XS0 (h1 tile never leaves LDS)
    lin12_kernel<<<GT, 256, 0, stream>>>(
        x, lin1_w, lin1_b, bn1_g, bn1_b, bn1_m, bn1_v,
        lin2_w, lin2_b, bn2_g, bn2_b, bn2_m, bn2_v, XS);
    for (int k = 0; k < KIT; ++k) {
      prop_kernel<<<GP2, 256, 0, stream>>>(XS + (size_t)k * NHF, XS, row_start,
                                           csr, XS + (size_t)(k + 1) * NHF);
    }
    // att1 with fused att2 + softmax (writes attw directly)
    mfma_dense2<256, 128, 64, 64, 2, false, __half, __half, true>
        <<<GT, 256, 0, stream>>>(
        XS, XS + (size_t)KIT * NHF, att1_w, att1_b, nullptr, nullptr, nullptr, nullptr,
        nullptr, (__half*)nullptr, att2_w, att2_b, attw);
    // fused head1+head2 with LDS-staged coalesced attention-gather -> out
    head12_kernel<<<GT, 256, 0, stream>>>(XS, attw, head1_w, head1_b,
                                          bn3_g, bn3_b, bn3_m, bn3_v,
                                          head2_w, head2_b, out);
  } else {
    float*  fusedF = (float*)alloc((size_t)NHF * 4);
    __half* base   = (__half*)alloc((size_t)NHF * 2);
    __half* hA     = (__half*)alloc((size_t)NHF * 2);
    __half* hB     = (__half*)alloc((size_t)NHF * 2);
    mfma_dense2<128, 128, 128, 128, 1, false, float, __half><<<GT, 256, 0, stream>>>(
        x, (const float*)nullptr, lin1_w, lin1_b, bn1_g, bn1_b, bn1_m, bn1_v, nullptr, h1);
    mfma_dense2<128, 128, 128, 128, 1, true, __half, __half><<<GT, 256, 0, stream>>>(
        h1, (const __half*)nullptr, lin2_w, lin2_b, bn2_g, bn2_b, bn2_m, bn2_v, h1, base);
    // pass 1: get xs10
    const __half* cur = base;
    for (int k = 1; k <= KIT; ++k) {
      __half* nxt = (k & 1) ? hA : hB;
      prop_kernel<<<GP2, 256, 0, stream>>>(cur, base, row_start, csr, nxt);
      cur = nxt;
    }
    mfma_dense2<256, 128, 64, 64, 2, false, __half, __half, true>
        <<<GT, 256, 0, stream>>>(
        base, cur, att1_w, att1_b, nullptr, nullptr, nullptr, nullptr,
        nullptr, (__half*)nullptr, att2_w, att2_b, attw);
    // pass 2: re-propagate, accumulate fused on the fly (fp32 accumulator)
    fused_accum_kernel<<<GP, 256, 0, stream>>>(base, attw, fusedF, 0);
    cur = base;
    for (int k = 1; k <= KIT; ++k) {
      __half* nxt = (k & 1) ? hA : hB;
      prop_kernel<<<GP2, 256, 0, stream>>>(cur, base, row_start, csr, nxt);
      fused_accum_kernel<<<GP, 256, 0, stream>>>(nxt, attw, fusedF, k);
      cur = nxt;
    }
    mfma_dense2<128, 128, 64, 64, 1, false, float, __half><<<GT, 256, 0, stream>>>(
        fusedF, (const float*)nullptr, head1_w, head1_b, bn3_g, bn3_b, bn3_m, bn3_v,
        nullptr, zbuf);
    mfma_dense2<64, 64, 48, 40, 0, false, __half, float><<<GT, 256, 0, stream>>>(
        zbuf, (const __half*)nullptr, head2_w, head2_b, nullptr, nullptr, nullptr, nullptr,
        nullptr, out);
  }
}